// Round 7
// baseline (255.366 us; speedup 1.0000x reference)
//
#include <hip/hip_runtime.h>

// MultiHeadSelfAttention: B=2, S=2048, E=768, H=12, D=64
// R7: flash = 2 consumer waves x 32 q-rows + 1 producer wave (192 thr).
//     Halves LDS read traffic vs R6 (fragments feed 2 MFMAs), ballot-skips
//     the O-rescale when no new row max, mask flags preloaded to a bitmask.
//     gemmQKV gets __launch_bounds__(256,3) for 3 blocks/CU.

typedef __bf16 bf16_t;
typedef bf16_t bf16x8 __attribute__((ext_vector_type(8)));
typedef bf16_t bf16x4 __attribute__((ext_vector_type(4)));
typedef float f32x4 __attribute__((ext_vector_type(4)));
typedef _Float16 f16x4 __attribute__((ext_vector_type(4)));

#define SC2 0.1803368801111137f  // 0.125 * log2(e): qk-scale folded into exp2

__device__ __forceinline__ float bf2f(unsigned short u) {
  union { unsigned int i; float f; } x;
  x.i = ((unsigned int)u) << 16;
  return x.f;
}

__device__ __forceinline__ void glds16(const bf16_t* g, bf16_t* l) {
  __builtin_amdgcn_global_load_lds(
      (const __attribute__((address_space(1))) void*)g,
      (__attribute__((address_space(3))) void*)l, 16, 0, 0);
}

// dtype probe: wave examines first 1024 u16 words of x. fp32 data => low
// halves carry random mantissa bits => wild bf16 exponents.
__device__ __forceinline__ int detect_bf16_flag(const unsigned short* x) {
  const int lane = threadIdx.x & 63;
  const uint4* p = (const uint4*)x;
  uint4 a = p[lane * 2];
  uint4 b = p[lane * 2 + 1];
  unsigned int w[8] = {a.x, a.y, a.z, a.w, b.x, b.y, b.z, b.w};
  unsigned int big = 0;
#pragma unroll
  for (int i = 0; i < 8; i++) {
    unsigned int e0 = (w[i] >> 7) & 0xFF, e1 = (w[i] >> 23) & 0xFF;
    big |= (e0 > 0x88u) | (e1 > 0x88u);
  }
  unsigned long long bal = __ballot(big != 0u);
  return bal == 0ULL ? 1 : 0;  // 1 => bf16 inputs
}

// ---------------------------------------------------------------- fused prep
// blocks [0,1536): x -> xb bf16 | [1536,3840): W transposes | [3840,4096): maskflags
__global__ void k_prep(const void* __restrict__ x, const void* __restrict__ mask,
                       const void* __restrict__ Wq, const void* __restrict__ Wk,
                       const void* __restrict__ Wv, const void* __restrict__ Wo,
                       bf16_t* __restrict__ xb, bf16_t* __restrict__ wqkvT,
                       bf16_t* __restrict__ woT, int* __restrict__ mflags) {
  __shared__ float ts[32][33];
  __shared__ int snz;
  const int blk = blockIdx.x;
  const int f = detect_bf16_flag((const unsigned short*)x);

  if (blk < 1536) {  // ---- ingest x
    int i = blk * 256 + threadIdx.x;
    if (f) {
      ((uint4*)xb)[i] = ((const uint4*)x)[i];
    } else {
      const float* xf = (const float*)x + (size_t)i * 8;
      bf16x8 v;
#pragma unroll
      for (int j = 0; j < 8; j++) v[j] = (bf16_t)xf[j];
      *(bf16x8*)(xb + (size_t)i * 8) = v;
    }
  } else if (blk < 3840) {  // ---- W transpose (4 matrices x 24x24 tiles)
    const int t = blk - 1536;
    const int z = t / 576, r = t % 576, kt = r / 24, nt = r % 24;
    const void* wsrc = (z == 0) ? Wq : (z == 1) ? Wk : (z == 2) ? Wv : Wo;
    bf16_t* dst = (z < 3) ? (wqkvT + (size_t)z * 768 * 768) : woT;
    const int c = threadIdx.x & 31, r0 = threadIdx.x >> 5;
#pragma unroll
    for (int i = 0; i < 4; i++) {
      int kr = kt * 32 + r0 + i * 8;
      float v;
      if (f) v = bf2f(((const unsigned short*)wsrc)[(size_t)kr * 768 + nt * 32 + c]);
      else   v = ((const float*)wsrc)[(size_t)kr * 768 + nt * 32 + c];
      ts[r0 + i * 8][c] = v;
    }
    __syncthreads();
#pragma unroll
    for (int i = 0; i < 4; i++) {
      int nr = nt * 32 + r0 + i * 8;
      dst[(size_t)nr * 768 + kt * 32 + c] = (bf16_t)ts[c][r0 + i * 8];
    }
  } else {  // ---- mask nonzero flag per 128x128 tile
    const int t = blk - 3840;
    const int qt = t >> 4, ktm = t & 15;
    if (threadIdx.x == 0) snz = 0;
    __syncthreads();
    int nz = 0;
    for (int i = 0; i < 64; i++) {
      int lin = i * 256 + threadIdx.x;
      int rr = lin >> 7, cc = lin & 127;
      size_t idx = (size_t)(qt * 128 + rr) * 2048 + ktm * 128 + cc;
      float v = f ? bf2f(((const unsigned short*)mask)[idx]) : ((const float*)mask)[idx];
      nz |= (v != 0.0f);
    }
    if (nz) snz = 1;
    __syncthreads();
    if (threadIdx.x == 0) mflags[qt * 16 + ktm] = snz;
  }
}

// ------------------------------------------------------------------ QKV GEMM
// C[4096 x 2304] = xb * wqkvT^T, 128x128 tile (m97 pattern), 3 blocks/CU.
// Epilogue: Q,K -> [b,h,s,d] bf16; V -> V^T [b,h,d,s] f16 via LDS transpose.
__global__ __launch_bounds__(256, 3) void k_gemmQKV(
    const bf16_t* __restrict__ A, const bf16_t* __restrict__ Bm,
    bf16_t* __restrict__ Qd, bf16_t* __restrict__ Kd, _Float16* __restrict__ Vt) {
  __shared__ __align__(16) char smem[17408];  // As(8K)+Bs(8K); reused 64x136 f16
  bf16_t* As = (bf16_t*)smem;
  bf16_t* Bs = (bf16_t*)(smem + 8192);
  _Float16* Tb = (_Float16*)smem;

  const int tid = threadIdx.x;
  const int n0 = blockIdx.x * 128, m0 = blockIdx.y * 128;
  const int r = tid >> 2, c8 = (tid & 3) << 3;
  const bf16_t* Ag = A + (size_t)(m0 + r) * 768 + c8;
  const bf16_t* Bg = Bm + (size_t)(n0 + r) * 768 + c8;
  const int wid = tid >> 6, lane = tid & 63;
  const int wm = (wid >> 1) << 6, wn = (wid & 1) << 6;
  const int lr = lane & 15, lk = (lane >> 4) << 3, g4 = (lane >> 4) << 2;

  f32x4 acc[4][4];
  const f32x4 z = {0.f, 0.f, 0.f, 0.f};
#pragma unroll
  for (int i = 0; i < 4; i++)
#pragma unroll
    for (int j = 0; j < 4; j++) acc[i][j] = z;

  for (int k0 = 0; k0 < 768; k0 += 32) {
    glds16(Ag + k0, As + wid * 512);
    glds16(Ag + (size_t)64 * 768 + k0, As + 2048 + wid * 512);
    glds16(Bg + k0, Bs + wid * 512);
    glds16(Bg + (size_t)64 * 768 + k0, Bs + 2048 + wid * 512);
    __syncthreads();
    bf16x8 af[4], bf_[4];
#pragma unroll
    for (int t = 0; t < 4; t++) af[t]  = *(const bf16x8*)&As[(wm + t * 16 + lr) * 32 + lk];
#pragma unroll
    for (int t = 0; t < 4; t++) bf_[t] = *(const bf16x8*)&Bs[(wn + t * 16 + lr) * 32 + lk];
#pragma unroll
    for (int i = 0; i < 4; i++)
#pragma unroll
      for (int j = 0; j < 4; j++)
        acc[i][j] = __builtin_amdgcn_mfma_f32_16x16x32_bf16(af[i], bf_[j], acc[i][j], 0, 0, 0);
    __syncthreads();
  }

  if (n0 < 1536) {  // Q or K: scatter (16-lane runs contiguous over d)
    bf16_t* dst = (n0 < 768) ? Qd : Kd;
    const int nb = (n0 < 768) ? n0 : n0 - 768;
    const int bb = m0 >> 11;
#pragma unroll
    for (int i = 0; i < 4; i++)
#pragma unroll
      for (int j = 0; j < 4; j++) {
        const int rc = nb + wn + j * 16 + lr;
        const int hh = rc >> 6, dd = rc & 63;
        const size_t base = (((size_t)bb * 12 + hh) * 2048) * 64 + dd;
#pragma unroll
        for (int reg = 0; reg < 4; reg++) {
          const int s = (m0 & 2047) + wm + i * 16 + g4 + reg;
          dst[base + (size_t)s * 64] = (bf16_t)acc[i][j][reg];
        }
      }
  } else {  // V: LDS transpose -> coalesced V^T f16 writes
    const int bb = m0 >> 11;
#pragma unroll
    for (int half = 0; half < 2; half++) {
      if ((wid & 1) == half) {
#pragma unroll
        for (int j = 0; j < 4; j++) {
          const int d_l = j * 16 + lr;
#pragma unroll
          for (int i = 0; i < 4; i++)
#pragma unroll
            for (int reg = 0; reg < 4; reg++)
              Tb[d_l * 136 + wm + i * 16 + g4 + reg] = (_Float16)acc[i][j][reg];
        }
      }
      __syncthreads();
      const int row = tid >> 2, cc = (tid & 3) * 32;
      const int vcol = (n0 - 1536) + half * 64 + row;
      const int hh = vcol >> 6;  // d == row
      _Float16* dstv = Vt + (((size_t)bb * 12 + hh) * 64 + row) * 2048 + (m0 & 2047) + cc;
#pragma unroll
      for (int u = 0; u < 4; u++)
        *(uint4*)(dstv + u * 8) = *(const uint4*)&Tb[row * 136 + cc + u * 8];
      __syncthreads();
    }
  }
}

// ----------------------------------------------------------- flash attention
// 768 blocks (XCD-swizzled) x 192 threads = 2 consumer waves (32 q-rows each,
// 2 q-groups) + 1 producer wave. Producer streams 64-key K (bf16 8KB) +
// V^T (f16 8KB) tiles global->VGPR->LDS double-buffered; consumers compute
// S^T = K*Q^T -> in-lane softmax (ballot-skipped rescale) -> O^T += V^T*P^T.
__global__ __launch_bounds__(192, 4) void k_flash(
    const bf16_t* __restrict__ Qd, const bf16_t* __restrict__ Kd,
    const _Float16* __restrict__ Vt, const void* __restrict__ mask,
    const int* __restrict__ mflags, const unsigned short* __restrict__ xdet,
    bf16_t* __restrict__ attn) {
  __shared__ __align__(16) char sm[32768];  // buf p at p*16384: K 8KB | V 8KB

  const int tid = threadIdx.x, wid = tid >> 6, lane = tid & 63;
  const int lr = lane & 15, quad = lane >> 4, lk = quad << 3, g4 = quad << 2;

  // XCD swizzle: 96 consecutive slots per XCD = 3 (b,h) pairs x 32 qtiles
  const int lin = blockIdx.x;
  const int gx = lin & 7, ww = lin >> 3;
  const int hb = gx * 3 + (ww >> 5);
  const int h = hb % 12, bb = hb / 12;
  const int qt = ww & 31;

  const size_t bh = (size_t)bb * 12 + h;
  const char* Kh = (const char*)(Kd + bh * 2048 * 64);
  const char* Vh = (const char*)(Vt + bh * 64 * 2048);

  if (wid == 2) {
    // ---------------- producer wave (identical staging maps to R6)
    const char* kS[8]; const char* vS[8];
#pragma unroll
    for (int u = 0; u < 8; u++) {
      const int R = (u >> 1) * 16 + lr;
      const int c = (u & 1) * 4 + quad;
      kS[u] = Kh + R * 128 + c * 16;
      const int u2 = u * 2 + (lane >> 5);
      const int dtv = u2 & 3, ctv = u2 >> 2, j2 = lane & 31;
      vS[u] = Vh + (size_t)(dtv * 16 + (j2 & 15)) * 4096 + ctv * 32 + (j2 >> 4) * 16;
    }
    uint4 kv[8], vv[8];
#pragma unroll
    for (int u = 0; u < 8; u++) kv[u] = *(const uint4*)(kS[u]);
#pragma unroll
    for (int u = 0; u < 8; u++) vv[u] = *(const uint4*)(vS[u]);
#pragma unroll
    for (int u = 0; u < 8; u++) *(uint4*)(sm + u * 1024 + lane * 16) = kv[u];
#pragma unroll
    for (int u = 0; u < 8; u++) *(uint4*)(sm + 8192 + u * 1024 + lane * 16) = vv[u];
    __syncthreads();  // buf0 ready
    for (int s = 0; s < 32; s++) {
      if (s < 31) {
        const int t = s + 1;
        char* buf = sm + (t & 1) * 16384;
#pragma unroll
        for (int u = 0; u < 8; u++) kv[u] = *(const uint4*)(kS[u] + (size_t)t * 8192);
#pragma unroll
        for (int u = 0; u < 8; u++) vv[u] = *(const uint4*)(vS[u] + (size_t)t * 128);
#pragma unroll
        for (int u = 0; u < 8; u++) *(uint4*)(buf + u * 1024 + lane * 16) = kv[u];
#pragma unroll
        for (int u = 0; u < 8; u++) *(uint4*)(buf + 8192 + u * 1024 + lane * 16) = vv[u];
      }
      __syncthreads();
    }
    return;
  }

  // ---------------- consumer waves (wid 0,1): 32 q-rows = 2 q-groups
  const bf16_t* Qh = Qd + bh * 2048 * 64;
  const int q0 = qt * 64 + wid * 32;
  const int mbf = detect_bf16_flag(xdet);
  const int* mfrow = mflags + (qt >> 1) * 16;
  int mbits = 0;
#pragma unroll
  for (int t = 0; t < 16; t++) mbits |= (mfrow[t] != 0) << t;  // preload flags

  bf16x8 qf[2][2];
#pragma unroll
  for (int qg = 0; qg < 2; qg++) {
    qf[qg][0] = *(const bf16x8*)&Qh[(size_t)(q0 + qg * 16 + lr) * 64 + lk];
    qf[qg][1] = *(const bf16x8*)&Qh[(size_t)(q0 + qg * 16 + lr) * 64 + 32 + lk];
  }

  const f32x4 z = {0.f, 0.f, 0.f, 0.f};
  f32x4 ot[2][4];
  float mrow[2] = {-1e30f, -1e30f}, lrow[2] = {0.f, 0.f};
#pragma unroll
  for (int qg = 0; qg < 2; qg++)
#pragma unroll
    for (int dt = 0; dt < 4; dt++) ot[qg][dt] = z;

  __syncthreads();  // wait buf0

  for (int s = 0; s < 32; s++) {
    const char* Kc = sm + (s & 1) * 16384;
    const char* Vc = Kc + 8192;

    // ---- S^T: sv[qg][ct] C-layout col=q(lr), row=key(ct*16+quad*4+reg)
    f32x4 sv[2][4];
#pragma unroll
    for (int qg = 0; qg < 2; qg++)
#pragma unroll
      for (int ct = 0; ct < 4; ct++) sv[qg][ct] = z;
#pragma unroll
    for (int ct = 0; ct < 4; ct++) {
      bf16x8 kf0 = *(const bf16x8*)(Kc + ct * 2048 + lane * 16);
      bf16x8 kf1 = *(const bf16x8*)(Kc + ct * 2048 + 1024 + lane * 16);
      sv[0][ct] = __builtin_amdgcn_mfma_f32_16x16x32_bf16(kf0, qf[0][0], sv[0][ct], 0, 0, 0);
      sv[0][ct] = __builtin_amdgcn_mfma_f32_16x16x32_bf16(kf1, qf[0][1], sv[0][ct], 0, 0, 0);
      sv[1][ct] = __builtin_amdgcn_mfma_f32_16x16x32_bf16(kf0, qf[1][0], sv[1][ct], 0, 0, 0);
      sv[1][ct] = __builtin_amdgcn_mfma_f32_16x16x32_bf16(kf1, qf[1][1], sv[1][ct], 0, 0, 0);
    }

    if ((mbits >> (s >> 1)) & 1) {  // generic additive mask
#pragma unroll
      for (int qg = 0; qg < 2; qg++)
#pragma unroll
        for (int ct = 0; ct < 4; ct++)
#pragma unroll
          for (int reg = 0; reg < 4; reg++) {
            size_t mi = (size_t)(q0 + qg * 16 + lr) * 2048 + s * 64 + ct * 16 + g4 + reg;
            float mv = mbf ? bf2f(((const unsigned short*)mask)[mi])
                           : ((const float*)mask)[mi];
            sv[qg][ct][reg] -= 8e9f * mv;
          }
    }

    // ---- row max per q-group + ballot-gated rescale
    float mnew[2];
#pragma unroll
    for (int qg = 0; qg < 2; qg++) {
      float t = fmaxf(
          fmaxf(fmaxf(fmaxf(sv[qg][0][0], sv[qg][0][1]), fmaxf(sv[qg][0][2], sv[qg][0][3])),
                fmaxf(fmaxf(sv[qg][1][0], sv[qg][1][1]), fmaxf(sv[qg][1][2], sv[qg][1][3]))),
          fmaxf(fmaxf(fmaxf(sv[qg][2][0], sv[qg][2][1]), fmaxf(sv[qg][2][2], sv[qg][2][3])),
                fmaxf(fmaxf(sv[qg][3][0], sv[qg][3][1]), fmaxf(sv[qg][3][2], sv[qg][3][3]))));
      t = fmaxf(t, __shfl_xor(t, 16));
      t = fmaxf(t, __shfl_xor(t, 32));
      mnew[qg] = fmaxf(mrow[qg], t);
    }
    if (__ballot((mnew[0] > mrow[0]) | (mnew[1] > mrow[1]))) {
#pragma unroll
      for (int qg = 0; qg < 2; qg++) {
        const float alpha = exp2f((mrow[qg] - mnew[qg]) * SC2);
#pragma unroll
        for (int dt = 0; dt < 4; dt++)
#pragma unroll
          for (int reg = 0; reg < 4; reg++) ot[qg][dt][reg] *= alpha;
        lrow[qg] *= alpha;
      }
    }
    mrow[0] = mnew[0]; mrow[1] = mnew[1];

    // ---- P^T = exp2(S^T*SC2 - mS) packed f16; row-sums
    f16x4 pb[2][4];
#pragma unroll
    for (int qg = 0; qg < 2; qg++) {
      const float mS = mnew[qg] * SC2;
      float rs = 0.f;
#pragma unroll
      for (int ct = 0; ct < 4; ct++) {
        float p0 = exp2f(fmaf(sv[qg][ct][0], SC2, -mS));
        float p1 = exp2f(fmaf(sv[qg][ct][1], SC2, -mS));
        float p2 = exp2f(fmaf(sv[qg][ct][2], SC2, -mS));
        float p3 = exp2f(fmaf(sv[qg][ct][3], SC2, -mS));
        rs += (p0 + p1) + (p2 + p3);
        f16x4 pk;
        pk[0] = (_Float16)p0; pk[1] = (_Float16)p1;
        pk[2] = (_Float16)p2; pk[3] = (_Float16)p3;
        pb[qg][ct] = pk;
      }
      rs += __shfl_xor(rs, 16);
      rs += __shfl_xor(rs, 32);
      lrow[qg] += rs;
    }

    // ---- PV: one V fragment read feeds both q-groups
#pragma unroll
    for (int ct = 0; ct < 4; ct++) {
#pragma unroll
      for (int dt = 0; dt < 4; dt++) {
        f16x4 va = *(const f16x4*)(Vc + (ct * 4 + dt) * 512 +
                                   (quad >> 1) * 256 + lr * 16 + (quad & 1) * 8);
        ot[0][dt] = __builtin_amdgcn_mfma_f32_16x16x16f16(va, pb[0][ct], ot[0][dt], 0, 0, 0);
        ot[1][dt] = __builtin_amdgcn_mfma_f32_16x16x16f16(va, pb[1][ct], ot[1][dt], 0, 0, 0);
      }
    }
    __syncthreads();  // release buf[s&1] to producer
  }

  // ---- normalize + store attn[b*2048+q][h*64+d]
#pragma unroll
  for (int qg = 0; qg < 2; qg++) {
    const float inv = 1.0f / lrow[qg];
    bf16_t* arow = attn + ((size_t)bb * 2048 + q0 + qg * 16 + lr) * 768 + h * 64 + g4;
#pragma unroll
    for (int dt = 0; dt < 4; dt++) {
      bf16x4 v;
#pragma unroll
      for (int reg = 0; reg < 4; reg++) v[reg] = (bf16_t)(ot[qg][dt][reg] * inv);
      *(bf16x4*)(arow + dt * 16) = v;
    }
  }
}

// -------------------------------------------------- output GEMM (attn @ Wo^T)
// 64x128 tiles -> 384 blocks; wave tile 32x64 (8 mfma/iter).
__global__ __launch_bounds__(256, 4) void k_gemm2(
    const bf16_t* __restrict__ A, const bf16_t* __restrict__ Bm,
    const void* __restrict__ bo, const unsigned short* __restrict__ xdet,
    float* __restrict__ outF, unsigned short* __restrict__ outH) {
  __shared__ __align__(16) bf16_t As[64 * 32];    // 4KB
  __shared__ __align__(16) bf16_t Bs[128 * 32];   // 8KB
  const int tid = threadIdx.x, wid = tid >> 6, lane = tid & 63;
  const int n0 = blockIdx.x * 128, m0 = blockIdx.y * 64;
  const int wm = (wid >> 1) * 32, wn = (wid & 1) * 64;
  const int lr = lane & 15, lk = (lane >> 4) << 3, g4 = (lane >> 4) << 2;
  const int rr = lane >> 2, c8 = (lane & 3) << 3;
  const bf16_t* Ag  = A + (size_t)(m0 + wid * 16 + rr) * 768 + c8;
  const bf16_t* Bg0 = Bm + (size_t)(n0 + wid * 32 + rr) * 768 + c8;
  const bf16_t* Bg1 = Bm + (size_t)(n0 + wid * 32 + 16 + rr) * 768 + c8;

  f32x4 acc[2][4];
  const f32x4 z = {0.f, 0.f, 0.f, 0.f};
#pragma unroll
  for (int i = 0; i < 2; i++)
#pragma unroll
    for (int j = 0; j < 4; j++) acc[i][j] = z;

  for (int k0 = 0; k0 < 768; k0 += 32) {
    glds16(Ag + k0, As + wid * 512);
    glds16(Bg0 + k0, Bs + wid * 1024);
    glds16(Bg1 + k0, Bs + wid * 1024 + 512);
    __syncthreads();
    bf16x8 af[2], bf_[4];
#pragma unroll
    for (int i = 0; i < 2; i++) af[i]  = *(const bf16x8*)&As[(wm + i * 16 + lr) * 32 + lk];
#pragma unroll
    for (int j = 0; j < 4; j++) bf_[j] = *(const bf16x8*)&Bs[(wn + j * 16 + lr) * 32 + lk];
#pragma unroll
    for (int i = 0; i < 2; i++)
#pragma unroll
      for (int j = 0; j < 4; j++)
        acc[i][j] = __builtin_amdgcn_mfma_f32_16x16x32_bf16(af[i], bf_[j], acc[i][j], 0, 0, 0);
    __syncthreads();
  }

  const int obf = detect_bf16_flag(xdet);
#pragma unroll
  for (int i = 0; i < 2; i++)
#pragma unroll
    for (int j = 0; j < 4; j++) {
      const int nn = n0 + wn + j * 16 + lr;
      const float bv = obf ? bf2f(((const unsigned short*)bo)[nn])
                           : ((const float*)bo)[nn];
#pragma unroll
      for (int reg = 0; reg < 4; reg++) {
        const int m = m0 + wm + i * 16 + g4 + reg;
        const float v = acc[i][j][reg] + bv;
        if (obf) outH[(size_t)m * 768 + nn] = __builtin_bit_cast(unsigned short, (bf16_t)v);
        else     outF[(size_t)m * 768 + nn] = v;
      }
    }
}

// -------------------------------------------------------------------- launch
extern "C" void kernel_launch(void* const* d_in, const int* in_sizes, int n_in,
                              void* d_out, int out_size, void* d_ws, size_t ws_size,
                              hipStream_t stream) {
  (void)in_sizes; (void)n_in; (void)out_size; (void)ws_size;
  const void* x    = d_in[0];
  const void* mask = d_in[1];
  const void* Wq   = d_in[2];
  const void* Wk   = d_in[3];
  const void* Wv   = d_in[4];
  const void* Wo   = d_in[5];
  const void* bo   = d_in[6];

  char* w = (char*)d_ws;
  size_t off = 0;
  auto take = [&](size_t b) -> void* {
    void* p = w + off;
    off = (off + b + 255) & ~(size_t)255;
    return p;
  };
  int*      mflags = (int*)take(256 * 4);
  bf16_t*   wqkvT  = (bf16_t*)take((size_t)2304 * 768 * 2);
  bf16_t*   woT    = (bf16_t*)take((size_t)768 * 768 * 2);
  bf16_t*   xb     = (bf16_t*)take((size_t)4096 * 768 * 2);
  bf16_t*   Qd     = (bf16_t*)take((size_t)3145728 * 2);
  bf16_t*   Kd     = (bf16_t*)take((size_t)3145728 * 2);
  _Float16* Vt     = (_Float16*)take((size_t)3145728 * 2);
  bf16_t*   attn   = xb;  // xb dead after QKV GEMM

  k_prep<<<4096, 256, 0, stream>>>(x, mask, Wq, Wk, Wv, Wo, xb, wqkvT, woT, mflags);
  k_gemmQKV<<<dim3(18, 32), 256, 0, stream>>>(xb, wqkvT, Qd, Kd, Vt);
  k_flash<<<768, 192, 0, stream>>>(Qd, Kd, Vt, mask, mflags,
                                   (const unsigned short*)x, attn);
  k_gemm2<<<dim3(6, 64), 256, 0, stream>>>(attn, woT, bo, (const unsigned short*)x,
                                           (float*)d_out, (unsigned short*)d_out);
}

// Round 8
// 227.490 us; speedup vs baseline: 1.1225x; 1.1225x over previous
//
#include <hip/hip_runtime.h>

// MultiHeadSelfAttention: B=2, S=2048, E=768, H=12, D=64
// R8: R7's 2-consumer (32 q-rows each) + 1 producer flash, with the spill
//     fixed: __launch_bounds__(192,2) (R7's (192,4) clamped VGPR to 64 and
//     spilled accumulators -> WRITE_SIZE tripled). Also v_cvt_pkrtz for P
//     packing. gemmQKV keeps (256,3). prep/gemm2 unchanged.

typedef __bf16 bf16_t;
typedef bf16_t bf16x8 __attribute__((ext_vector_type(8)));
typedef bf16_t bf16x4 __attribute__((ext_vector_type(4)));
typedef float f32x4 __attribute__((ext_vector_type(4)));
typedef _Float16 f16x4 __attribute__((ext_vector_type(4)));
typedef __fp16 hf2 __attribute__((ext_vector_type(2)));

#define SC2 0.1803368801111137f  // 0.125 * log2(e): qk-scale folded into exp2

__device__ __forceinline__ float bf2f(unsigned short u) {
  union { unsigned int i; float f; } x;
  x.i = ((unsigned int)u) << 16;
  return x.f;
}

__device__ __forceinline__ void glds16(const bf16_t* g, bf16_t* l) {
  __builtin_amdgcn_global_load_lds(
      (const __attribute__((address_space(1))) void*)g,
      (__attribute__((address_space(3))) void*)l, 16, 0, 0);
}

// dtype probe: wave examines first 1024 u16 words of x. fp32 data => low
// halves carry random mantissa bits => wild bf16 exponents.
__device__ __forceinline__ int detect_bf16_flag(const unsigned short* x) {
  const int lane = threadIdx.x & 63;
  const uint4* p = (const uint4*)x;
  uint4 a = p[lane * 2];
  uint4 b = p[lane * 2 + 1];
  unsigned int w[8] = {a.x, a.y, a.z, a.w, b.x, b.y, b.z, b.w};
  unsigned int big = 0;
#pragma unroll
  for (int i = 0; i < 8; i++) {
    unsigned int e0 = (w[i] >> 7) & 0xFF, e1 = (w[i] >> 23) & 0xFF;
    big |= (e0 > 0x88u) | (e1 > 0x88u);
  }
  unsigned long long bal = __ballot(big != 0u);
  return bal == 0ULL ? 1 : 0;  // 1 => bf16 inputs
}

// ---------------------------------------------------------------- fused prep
// blocks [0,1536): x -> xb bf16 | [1536,3840): W transposes | [3840,4096): maskflags
__global__ void k_prep(const void* __restrict__ x, const void* __restrict__ mask,
                       const void* __restrict__ Wq, const void* __restrict__ Wk,
                       const void* __restrict__ Wv, const void* __restrict__ Wo,
                       bf16_t* __restrict__ xb, bf16_t* __restrict__ wqkvT,
                       bf16_t* __restrict__ woT, int* __restrict__ mflags) {
  __shared__ float ts[32][33];
  __shared__ int snz;
  const int blk = blockIdx.x;
  const int f = detect_bf16_flag((const unsigned short*)x);

  if (blk < 1536) {  // ---- ingest x
    int i = blk * 256 + threadIdx.x;
    if (f) {
      ((uint4*)xb)[i] = ((const uint4*)x)[i];
    } else {
      const float* xf = (const float*)x + (size_t)i * 8;
      bf16x8 v;
#pragma unroll
      for (int j = 0; j < 8; j++) v[j] = (bf16_t)xf[j];
      *(bf16x8*)(xb + (size_t)i * 8) = v;
    }
  } else if (blk < 3840) {  // ---- W transpose (4 matrices x 24x24 tiles)
    const int t = blk - 1536;
    const int z = t / 576, r = t % 576, kt = r / 24, nt = r % 24;
    const void* wsrc = (z == 0) ? Wq : (z == 1) ? Wk : (z == 2) ? Wv : Wo;
    bf16_t* dst = (z < 3) ? (wqkvT + (size_t)z * 768 * 768) : woT;
    const int c = threadIdx.x & 31, r0 = threadIdx.x >> 5;
#pragma unroll
    for (int i = 0; i < 4; i++) {
      int kr = kt * 32 + r0 + i * 8;
      float v;
      if (f) v = bf2f(((const unsigned short*)wsrc)[(size_t)kr * 768 + nt * 32 + c]);
      else   v = ((const float*)wsrc)[(size_t)kr * 768 + nt * 32 + c];
      ts[r0 + i * 8][c] = v;
    }
    __syncthreads();
#pragma unroll
    for (int i = 0; i < 4; i++) {
      int nr = nt * 32 + r0 + i * 8;
      dst[(size_t)nr * 768 + kt * 32 + c] = (bf16_t)ts[c][r0 + i * 8];
    }
  } else {  // ---- mask nonzero flag per 128x128 tile
    const int t = blk - 3840;
    const int qt = t >> 4, ktm = t & 15;
    if (threadIdx.x == 0) snz = 0;
    __syncthreads();
    int nz = 0;
    for (int i = 0; i < 64; i++) {
      int lin = i * 256 + threadIdx.x;
      int rr = lin >> 7, cc = lin & 127;
      size_t idx = (size_t)(qt * 128 + rr) * 2048 + ktm * 128 + cc;
      float v = f ? bf2f(((const unsigned short*)mask)[idx]) : ((const float*)mask)[idx];
      nz |= (v != 0.0f);
    }
    if (nz) snz = 1;
    __syncthreads();
    if (threadIdx.x == 0) mflags[qt * 16 + ktm] = snz;
  }
}

// ------------------------------------------------------------------ QKV GEMM
// C[4096 x 2304] = xb * wqkvT^T, 128x128 tile (m97 pattern), 3 blocks/CU.
// Epilogue: Q,K -> [b,h,s,d] bf16; V -> V^T [b,h,d,s] f16 via LDS transpose.
__global__ __launch_bounds__(256, 3) void k_gemmQKV(
    const bf16_t* __restrict__ A, const bf16_t* __restrict__ Bm,
    bf16_t* __restrict__ Qd, bf16_t* __restrict__ Kd, _Float16* __restrict__ Vt) {
  __shared__ __align__(16) char smem[17408];  // As(8K)+Bs(8K); reused 64x136 f16
  bf16_t* As = (bf16_t*)smem;
  bf16_t* Bs = (bf16_t*)(smem + 8192);
  _Float16* Tb = (_Float16*)smem;

  const int tid = threadIdx.x;
  const int n0 = blockIdx.x * 128, m0 = blockIdx.y * 128;
  const int r = tid >> 2, c8 = (tid & 3) << 3;
  const bf16_t* Ag = A + (size_t)(m0 + r) * 768 + c8;
  const bf16_t* Bg = Bm + (size_t)(n0 + r) * 768 + c8;
  const int wid = tid >> 6, lane = tid & 63;
  const int wm = (wid >> 1) << 6, wn = (wid & 1) << 6;
  const int lr = lane & 15, lk = (lane >> 4) << 3, g4 = (lane >> 4) << 2;

  f32x4 acc[4][4];
  const f32x4 z = {0.f, 0.f, 0.f, 0.f};
#pragma unroll
  for (int i = 0; i < 4; i++)
#pragma unroll
    for (int j = 0; j < 4; j++) acc[i][j] = z;

  for (int k0 = 0; k0 < 768; k0 += 32) {
    glds16(Ag + k0, As + wid * 512);
    glds16(Ag + (size_t)64 * 768 + k0, As + 2048 + wid * 512);
    glds16(Bg + k0, Bs + wid * 512);
    glds16(Bg + (size_t)64 * 768 + k0, Bs + 2048 + wid * 512);
    __syncthreads();
    bf16x8 af[4], bf_[4];
#pragma unroll
    for (int t = 0; t < 4; t++) af[t]  = *(const bf16x8*)&As[(wm + t * 16 + lr) * 32 + lk];
#pragma unroll
    for (int t = 0; t < 4; t++) bf_[t] = *(const bf16x8*)&Bs[(wn + t * 16 + lr) * 32 + lk];
#pragma unroll
    for (int i = 0; i < 4; i++)
#pragma unroll
      for (int j = 0; j < 4; j++)
        acc[i][j] = __builtin_amdgcn_mfma_f32_16x16x32_bf16(af[i], bf_[j], acc[i][j], 0, 0, 0);
    __syncthreads();
  }

  if (n0 < 1536) {  // Q or K: scatter (16-lane runs contiguous over d)
    bf16_t* dst = (n0 < 768) ? Qd : Kd;
    const int nb = (n0 < 768) ? n0 : n0 - 768;
    const int bb = m0 >> 11;
#pragma unroll
    for (int i = 0; i < 4; i++)
#pragma unroll
      for (int j = 0; j < 4; j++) {
        const int rc = nb + wn + j * 16 + lr;
        const int hh = rc >> 6, dd = rc & 63;
        const size_t base = (((size_t)bb * 12 + hh) * 2048) * 64 + dd;
#pragma unroll
        for (int reg = 0; reg < 4; reg++) {
          const int s = (m0 & 2047) + wm + i * 16 + g4 + reg;
          dst[base + (size_t)s * 64] = (bf16_t)acc[i][j][reg];
        }
      }
  } else {  // V: LDS transpose -> coalesced V^T f16 writes
    const int bb = m0 >> 11;
#pragma unroll
    for (int half = 0; half < 2; half++) {
      if ((wid & 1) == half) {
#pragma unroll
        for (int j = 0; j < 4; j++) {
          const int d_l = j * 16 + lr;
#pragma unroll
          for (int i = 0; i < 4; i++)
#pragma unroll
            for (int reg = 0; reg < 4; reg++)
              Tb[d_l * 136 + wm + i * 16 + g4 + reg] = (_Float16)acc[i][j][reg];
        }
      }
      __syncthreads();
      const int row = tid >> 2, cc = (tid & 3) * 32;
      const int vcol = (n0 - 1536) + half * 64 + row;
      const int hh = vcol >> 6;  // d == row
      _Float16* dstv = Vt + (((size_t)bb * 12 + hh) * 64 + row) * 2048 + (m0 & 2047) + cc;
#pragma unroll
      for (int u = 0; u < 4; u++)
        *(uint4*)(dstv + u * 8) = *(const uint4*)&Tb[row * 136 + cc + u * 8];
      __syncthreads();
    }
  }
}

// ----------------------------------------------------------- flash attention
// 768 blocks (XCD-swizzled) x 192 threads = 2 consumer waves (32 q-rows each,
// 2 q-groups) + 1 producer wave. Producer streams 64-key K (bf16 8KB) +
// V^T (f16 8KB) tiles global->VGPR->LDS double-buffered; consumers compute
// S^T = K*Q^T -> in-lane softmax (ballot-gated rescale, pkrtz P packing) ->
// O^T += V^T*P^T. launch_bounds(192,2): 256-VGPR cap, no spill (R7 lesson).
__global__ __launch_bounds__(192, 2) void k_flash(
    const bf16_t* __restrict__ Qd, const bf16_t* __restrict__ Kd,
    const _Float16* __restrict__ Vt, const void* __restrict__ mask,
    const int* __restrict__ mflags, const unsigned short* __restrict__ xdet,
    bf16_t* __restrict__ attn) {
  __shared__ __align__(16) char sm[32768];  // buf p at p*16384: K 8KB | V 8KB

  const int tid = threadIdx.x, wid = tid >> 6, lane = tid & 63;
  const int lr = lane & 15, quad = lane >> 4, lk = quad << 3, g4 = quad << 2;

  // XCD swizzle: 96 consecutive slots per XCD = 3 (b,h) pairs x 32 qtiles
  const int lin = blockIdx.x;
  const int gx = lin & 7, ww = lin >> 3;
  const int hb = gx * 3 + (ww >> 5);
  const int h = hb % 12, bb = hb / 12;
  const int qt = ww & 31;

  const size_t bh = (size_t)bb * 12 + h;
  const char* Kh = (const char*)(Kd + bh * 2048 * 64);
  const char* Vh = (const char*)(Vt + bh * 64 * 2048);

  if (wid == 2) {
    // ---------------- producer wave (identical staging maps to R6)
    const char* kS[8]; const char* vS[8];
#pragma unroll
    for (int u = 0; u < 8; u++) {
      const int R = (u >> 1) * 16 + lr;
      const int c = (u & 1) * 4 + quad;
      kS[u] = Kh + R * 128 + c * 16;
      const int u2 = u * 2 + (lane >> 5);
      const int dtv = u2 & 3, ctv = u2 >> 2, j2 = lane & 31;
      vS[u] = Vh + (size_t)(dtv * 16 + (j2 & 15)) * 4096 + ctv * 32 + (j2 >> 4) * 16;
    }
    uint4 kv[8], vv[8];
#pragma unroll
    for (int u = 0; u < 8; u++) kv[u] = *(const uint4*)(kS[u]);
#pragma unroll
    for (int u = 0; u < 8; u++) vv[u] = *(const uint4*)(vS[u]);
#pragma unroll
    for (int u = 0; u < 8; u++) *(uint4*)(sm + u * 1024 + lane * 16) = kv[u];
#pragma unroll
    for (int u = 0; u < 8; u++) *(uint4*)(sm + 8192 + u * 1024 + lane * 16) = vv[u];
    __syncthreads();  // buf0 ready
    for (int s = 0; s < 32; s++) {
      if (s < 31) {
        const int t = s + 1;
        char* buf = sm + (t & 1) * 16384;
#pragma unroll
        for (int u = 0; u < 8; u++) kv[u] = *(const uint4*)(kS[u] + (size_t)t * 8192);
#pragma unroll
        for (int u = 0; u < 8; u++) vv[u] = *(const uint4*)(vS[u] + (size_t)t * 128);
#pragma unroll
        for (int u = 0; u < 8; u++) *(uint4*)(buf + u * 1024 + lane * 16) = kv[u];
#pragma unroll
        for (int u = 0; u < 8; u++) *(uint4*)(buf + 8192 + u * 1024 + lane * 16) = vv[u];
      }
      __syncthreads();
    }
    return;
  }

  // ---------------- consumer waves (wid 0,1): 32 q-rows = 2 q-groups
  const bf16_t* Qh = Qd + bh * 2048 * 64;
  const int q0 = qt * 64 + wid * 32;
  const int mbf = detect_bf16_flag(xdet);
  const int* mfrow = mflags + (qt >> 1) * 16;
  int mbits = 0;
#pragma unroll
  for (int t = 0; t < 16; t++) mbits |= (mfrow[t] != 0) << t;  // preload flags

  bf16x8 qf[2][2];
#pragma unroll
  for (int qg = 0; qg < 2; qg++) {
    qf[qg][0] = *(const bf16x8*)&Qh[(size_t)(q0 + qg * 16 + lr) * 64 + lk];
    qf[qg][1] = *(const bf16x8*)&Qh[(size_t)(q0 + qg * 16 + lr) * 64 + 32 + lk];
  }

  const f32x4 z = {0.f, 0.f, 0.f, 0.f};
  f32x4 ot[2][4];
  float mrow[2] = {-1e30f, -1e30f}, lrow[2] = {0.f, 0.f};
#pragma unroll
  for (int qg = 0; qg < 2; qg++)
#pragma unroll
    for (int dt = 0; dt < 4; dt++) ot[qg][dt] = z;

  __syncthreads();  // wait buf0

  for (int s = 0; s < 32; s++) {
    const char* Kc = sm + (s & 1) * 16384;
    const char* Vc = Kc + 8192;

    // ---- S^T: sv[qg][ct] C-layout col=q(lr), row=key(ct*16+quad*4+reg)
    f32x4 sv[2][4];
#pragma unroll
    for (int qg = 0; qg < 2; qg++)
#pragma unroll
      for (int ct = 0; ct < 4; ct++) sv[qg][ct] = z;
#pragma unroll
    for (int ct = 0; ct < 4; ct++) {
      bf16x8 kf0 = *(const bf16x8*)(Kc + ct * 2048 + lane * 16);
      bf16x8 kf1 = *(const bf16x8*)(Kc + ct * 2048 + 1024 + lane * 16);
      sv[0][ct] = __builtin_amdgcn_mfma_f32_16x16x32_bf16(kf0, qf[0][0], sv[0][ct], 0, 0, 0);
      sv[0][ct] = __builtin_amdgcn_mfma_f32_16x16x32_bf16(kf1, qf[0][1], sv[0][ct], 0, 0, 0);
      sv[1][ct] = __builtin_amdgcn_mfma_f32_16x16x32_bf16(kf0, qf[1][0], sv[1][ct], 0, 0, 0);
      sv[1][ct] = __builtin_amdgcn_mfma_f32_16x16x32_bf16(kf1, qf[1][1], sv[1][ct], 0, 0, 0);
    }

    if ((mbits >> (s >> 1)) & 1) {  // generic additive mask
#pragma unroll
      for (int qg = 0; qg < 2; qg++)
#pragma unroll
        for (int ct = 0; ct < 4; ct++)
#pragma unroll
          for (int reg = 0; reg < 4; reg++) {
            size_t mi = (size_t)(q0 + qg * 16 + lr) * 2048 + s * 64 + ct * 16 + g4 + reg;
            float mv = mbf ? bf2f(((const unsigned short*)mask)[mi])
                           : ((const float*)mask)[mi];
            sv[qg][ct][reg] -= 8e9f * mv;
          }
    }

    // ---- row max per q-group + ballot-gated rescale
    float mnew[2];
#pragma unroll
    for (int qg = 0; qg < 2; qg++) {
      float t = fmaxf(
          fmaxf(fmaxf(fmaxf(sv[qg][0][0], sv[qg][0][1]), fmaxf(sv[qg][0][2], sv[qg][0][3])),
                fmaxf(fmaxf(sv[qg][1][0], sv[qg][1][1]), fmaxf(sv[qg][1][2], sv[qg][1][3]))),
          fmaxf(fmaxf(fmaxf(sv[qg][2][0], sv[qg][2][1]), fmaxf(sv[qg][2][2], sv[qg][2][3])),
                fmaxf(fmaxf(sv[qg][3][0], sv[qg][3][1]), fmaxf(sv[qg][3][2], sv[qg][3][3]))));
      t = fmaxf(t, __shfl_xor(t, 16));
      t = fmaxf(t, __shfl_xor(t, 32));
      mnew[qg] = fmaxf(mrow[qg], t);
    }
    if (__ballot((mnew[0] > mrow[0]) | (mnew[1] > mrow[1]))) {
#pragma unroll
      for (int qg = 0; qg < 2; qg++) {
        const float alpha = exp2f((mrow[qg] - mnew[qg]) * SC2);
#pragma unroll
        for (int dt = 0; dt < 4; dt++)
#pragma unroll
          for (int reg = 0; reg < 4; reg++) ot[qg][dt][reg] *= alpha;
        lrow[qg] *= alpha;
      }
    }
    mrow[0] = mnew[0]; mrow[1] = mnew[1];

    // ---- P^T = exp2(S^T*SC2 - mS), packed f16 via v_cvt_pkrtz; row-sums
    f16x4 pb[2][4];
#pragma unroll
    for (int qg = 0; qg < 2; qg++) {
      const float mS = mnew[qg] * SC2;
      float rs = 0.f;
#pragma unroll
      for (int ct = 0; ct < 4; ct++) {
        float p0 = exp2f(fmaf(sv[qg][ct][0], SC2, -mS));
        float p1 = exp2f(fmaf(sv[qg][ct][1], SC2, -mS));
        float p2 = exp2f(fmaf(sv[qg][ct][2], SC2, -mS));
        float p3 = exp2f(fmaf(sv[qg][ct][3], SC2, -mS));
        rs += (p0 + p1) + (p2 + p3);
        union { hf2 h[2]; f16x4 v; } u;
        u.h[0] = __builtin_amdgcn_cvt_pkrtz(p0, p1);
        u.h[1] = __builtin_amdgcn_cvt_pkrtz(p2, p3);
        pb[qg][ct] = u.v;
      }
      rs += __shfl_xor(rs, 16);
      rs += __shfl_xor(rs, 32);
      lrow[qg] += rs;
    }

    // ---- PV: one V fragment read feeds both q-groups
#pragma unroll
    for (int ct = 0; ct < 4; ct++) {
#pragma unroll
      for (int dt = 0; dt < 4; dt++) {
        f16x4 va = *(const f16x4*)(Vc + (ct * 4 + dt) * 512 +
                                   (quad >> 1) * 256 + lr * 16 + (quad & 1) * 8);
        ot[0][dt] = __builtin_amdgcn_mfma_f32_16x16x16f16(va, pb[0][ct], ot[0][dt], 0, 0, 0);
        ot[1][dt] = __builtin_amdgcn_mfma_f32_16x16x16f16(va, pb[1][ct], ot[1][dt], 0, 0, 0);
      }
    }
    __syncthreads();  // release buf[s&1] to producer
  }

  // ---- normalize + store attn[b*2048+q][h*64+d]
#pragma unroll
  for (int qg = 0; qg < 2; qg++) {
    const float inv = 1.0f / lrow[qg];
    bf16_t* arow = attn + ((size_t)bb * 2048 + q0 + qg * 16 + lr) * 768 + h * 64 + g4;
#pragma unroll
    for (int dt = 0; dt < 4; dt++) {
      bf16x4 v;
#pragma unroll
      for (int reg = 0; reg < 4; reg++) v[reg] = (bf16_t)(ot[qg][dt][reg] * inv);
      *(bf16x4*)(arow + dt * 16) = v;
    }
  }
}

// -------------------------------------------------- output GEMM (attn @ Wo^T)
// 64x128 tiles -> 384 blocks; wave tile 32x64 (8 mfma/iter).
__global__ __launch_bounds__(256, 4) void k_gemm2(
    const bf16_t* __restrict__ A, const bf16_t* __restrict__ Bm,
    const void* __restrict__ bo, const unsigned short* __restrict__ xdet,
    float* __restrict__ outF, unsigned short* __restrict__ outH) {
  __shared__ __align__(16) bf16_t As[64 * 32];    // 4KB
  __shared__ __align__(16) bf16_t Bs[128 * 32];   // 8KB
  const int tid = threadIdx.x, wid = tid >> 6, lane = tid & 63;
  const int n0 = blockIdx.x * 128, m0 = blockIdx.y * 64;
  const int wm = (wid >> 1) * 32, wn = (wid & 1) * 64;
  const int lr = lane & 15, lk = (lane >> 4) << 3, g4 = (lane >> 4) << 2;
  const int rr = lane >> 2, c8 = (lane & 3) << 3;
  const bf16_t* Ag  = A + (size_t)(m0 + wid * 16 + rr) * 768 + c8;
  const bf16_t* Bg0 = Bm + (size_t)(n0 + wid * 32 + rr) * 768 + c8;
  const bf16_t* Bg1 = Bm + (size_t)(n0 + wid * 32 + 16 + rr) * 768 + c8;

  f32x4 acc[2][4];
  const f32x4 z = {0.f, 0.f, 0.f, 0.f};
#pragma unroll
  for (int i = 0; i < 2; i++)
#pragma unroll
    for (int j = 0; j < 4; j++) acc[i][j] = z;

  for (int k0 = 0; k0 < 768; k0 += 32) {
    glds16(Ag + k0, As + wid * 512);
    glds16(Bg0 + k0, Bs + wid * 1024);
    glds16(Bg1 + k0, Bs + wid * 1024 + 512);
    __syncthreads();
    bf16x8 af[2], bf_[4];
#pragma unroll
    for (int i = 0; i < 2; i++) af[i]  = *(const bf16x8*)&As[(wm + i * 16 + lr) * 32 + lk];
#pragma unroll
    for (int j = 0; j < 4; j++) bf_[j] = *(const bf16x8*)&Bs[(wn + j * 16 + lr) * 32 + lk];
#pragma unroll
    for (int i = 0; i < 2; i++)
#pragma unroll
      for (int j = 0; j < 4; j++)
        acc[i][j] = __builtin_amdgcn_mfma_f32_16x16x32_bf16(af[i], bf_[j], acc[i][j], 0, 0, 0);
    __syncthreads();
  }

  const int obf = detect_bf16_flag(xdet);
#pragma unroll
  for (int i = 0; i < 2; i++)
#pragma unroll
    for (int j = 0; j < 4; j++) {
      const int nn = n0 + wn + j * 16 + lr;
      const float bv = obf ? bf2f(((const unsigned short*)bo)[nn])
                           : ((const float*)bo)[nn];
#pragma unroll
      for (int reg = 0; reg < 4; reg++) {
        const int m = m0 + wm + i * 16 + g4 + reg;
        const float v = acc[i][j][reg] + bv;
        if (obf) outH[(size_t)m * 768 + nn] = __builtin_bit_cast(unsigned short, (bf16_t)v);
        else     outF[(size_t)m * 768 + nn] = v;
      }
    }
}

// -------------------------------------------------------------------- launch
extern "C" void kernel_launch(void* const* d_in, const int* in_sizes, int n_in,
                              void* d_out, int out_size, void* d_ws, size_t ws_size,
                              hipStream_t stream) {
  (void)in_sizes; (void)n_in; (void)out_size; (void)ws_size;
  const void* x    = d_in[0];
  const void* mask = d_in[1];
  const void* Wq   = d_in[2];
  const void* Wk   = d_in[3];
  const void* Wv   = d_in[4];
  const void* Wo   = d_in[5];
  const void* bo   = d_in[6];

  char* w = (char*)d_ws;
  size_t off = 0;
  auto take = [&](size_t b) -> void* {
    void* p = w + off;
    off = (off + b + 255) & ~(size_t)255;
    return p;
  };
  int*      mflags = (int*)take(256 * 4);
  bf16_t*   wqkvT  = (bf16_t*)take((size_t)2304 * 768 * 2);
  bf16_t*   woT    = (bf16_t*)take((size_t)768 * 768 * 2);
  bf16_t*   xb     = (bf16_t*)take((size_t)4096 * 768 * 2);
  bf16_t*   Qd     = (bf16_t*)take((size_t)3145728 * 2);
  bf16_t*   Kd     = (bf16_t*)take((size_t)3145728 * 2);
  _Float16* Vt     = (_Float16*)take((size_t)3145728 * 2);
  bf16_t*   attn   = xb;  // xb dead after QKV GEMM

  k_prep<<<4096, 256, 0, stream>>>(x, mask, Wq, Wk, Wv, Wo, xb, wqkvT, woT, mflags);
  k_gemmQKV<<<dim3(18, 32), 256, 0, stream>>>(xb, wqkvT, Qd, Kd, Vt);
  k_flash<<<768, 192, 0, stream>>>(Qd, Kd, Vt, mask, mflags,
                                   (const unsigned short*)x, attn);
  k_gemm2<<<dim3(6, 64), 256, 0, stream>>>(attn, woT, bo, (const unsigned short*)x,
                                           (float*)d_out, (unsigned short*)d_out);
}

// Round 9
// 186.465 us; speedup vs baseline: 1.3695x; 1.2200x over previous
//
#include <hip/hip_runtime.h>

// MultiHeadSelfAttention: B=2, S=2048, E=768, H=12, D=64
// R9: R6's proven 4-consumer + producer flash (70.6us) with VALU cuts:
//     raw v_exp_f32 (__builtin_amdgcn_exp2f), pkrtz P packing, mask-bitmask
//     preload, ballot-gated rescale. prep: bf16 fast-path skips x copy
//     (gemmQKV selects x vs xb on device); maskflags vectorized uint4.

typedef __bf16 bf16_t;
typedef bf16_t bf16x8 __attribute__((ext_vector_type(8)));
typedef bf16_t bf16x4 __attribute__((ext_vector_type(4)));
typedef float f32x4 __attribute__((ext_vector_type(4)));
typedef _Float16 f16x4 __attribute__((ext_vector_type(4)));
typedef __fp16 hf2 __attribute__((ext_vector_type(2)));

#define SC2 0.1803368801111137f  // 0.125 * log2(e): qk-scale folded into exp2

__device__ __forceinline__ float bf2f(unsigned short u) {
  union { unsigned int i; float f; } x;
  x.i = ((unsigned int)u) << 16;
  return x.f;
}

__device__ __forceinline__ float fexp2(float x) {
  return __builtin_amdgcn_exp2f(x);  // raw v_exp_f32; args <= 0 here, FTZ exact
}

__device__ __forceinline__ void glds16(const bf16_t* g, bf16_t* l) {
  __builtin_amdgcn_global_load_lds(
      (const __attribute__((address_space(1))) void*)g,
      (__attribute__((address_space(3))) void*)l, 16, 0, 0);
}

// dtype probe: wave examines first 1024 u16 words of x. fp32 data => low
// halves carry random mantissa bits => wild bf16 exponents.
__device__ __forceinline__ int detect_bf16_flag(const unsigned short* x) {
  const int lane = threadIdx.x & 63;
  const uint4* p = (const uint4*)x;
  uint4 a = p[lane * 2];
  uint4 b = p[lane * 2 + 1];
  unsigned int w[8] = {a.x, a.y, a.z, a.w, b.x, b.y, b.z, b.w};
  unsigned int big = 0;
#pragma unroll
  for (int i = 0; i < 8; i++) {
    unsigned int e0 = (w[i] >> 7) & 0xFF, e1 = (w[i] >> 23) & 0xFF;
    big |= (e0 > 0x88u) | (e1 > 0x88u);
  }
  unsigned long long bal = __ballot(big != 0u);
  return bal == 0ULL ? 1 : 0;  // 1 => bf16 inputs
}

// ---------------------------------------------------------------- fused prep
// blocks [0,1536): x -> xb bf16 (skipped when bf16) | [1536,3840): W transposes
// | [3840,4096): maskflags (vectorized uint4 scan)
__global__ void k_prep(const void* __restrict__ x, const void* __restrict__ mask,
                       const void* __restrict__ Wq, const void* __restrict__ Wk,
                       const void* __restrict__ Wv, const void* __restrict__ Wo,
                       bf16_t* __restrict__ xb, bf16_t* __restrict__ wqkvT,
                       bf16_t* __restrict__ woT, int* __restrict__ mflags) {
  __shared__ float ts[32][33];
  __shared__ int snz;
  const int blk = blockIdx.x;
  const int f = detect_bf16_flag((const unsigned short*)x);

  if (blk < 1536) {  // ---- ingest x (fp32 only; bf16 path reads x directly)
    if (f) return;
    int i = blk * 256 + threadIdx.x;
    const float* xf = (const float*)x + (size_t)i * 8;
    bf16x8 v;
#pragma unroll
    for (int j = 0; j < 8; j++) v[j] = (bf16_t)xf[j];
    *(bf16x8*)(xb + (size_t)i * 8) = v;
  } else if (blk < 3840) {  // ---- W transpose (4 matrices x 24x24 tiles)
    const int t = blk - 1536;
    const int z = t / 576, r = t % 576, kt = r / 24, nt = r % 24;
    const void* wsrc = (z == 0) ? Wq : (z == 1) ? Wk : (z == 2) ? Wv : Wo;
    bf16_t* dst = (z < 3) ? (wqkvT + (size_t)z * 768 * 768) : woT;
    const int c = threadIdx.x & 31, r0 = threadIdx.x >> 5;
#pragma unroll
    for (int i = 0; i < 4; i++) {
      int kr = kt * 32 + r0 + i * 8;
      float v;
      if (f) v = bf2f(((const unsigned short*)wsrc)[(size_t)kr * 768 + nt * 32 + c]);
      else   v = ((const float*)wsrc)[(size_t)kr * 768 + nt * 32 + c];
      ts[r0 + i * 8][c] = v;
    }
    __syncthreads();
#pragma unroll
    for (int i = 0; i < 4; i++) {
      int nr = nt * 32 + r0 + i * 8;
      dst[(size_t)nr * 768 + kt * 32 + c] = (bf16_t)ts[c][r0 + i * 8];
    }
  } else {  // ---- mask nonzero flag per 128x128 tile, uint4 loads
    const int t = blk - 3840;
    const int qt = t >> 4, ktm = t & 15;
    if (threadIdx.x == 0) snz = 0;
    __syncthreads();
    unsigned int nz = 0;
    if (f) {  // bf16 mask: tile row = 128*2B; 128 rows x 16 uint4
#pragma unroll
      for (int i = 0; i < 8; i++) {
        int uidx = i * 256 + threadIdx.x;
        int row = uidx >> 4, col = uidx & 15;
        const uint4* p = (const uint4*)((const char*)mask +
            ((size_t)(qt * 128 + row) * 2048 + ktm * 128) * 2 + col * 16);
        uint4 v = *p;
        nz |= ((v.x | v.y | v.z | v.w) & 0x7fff7fffu);
      }
    } else {  // fp32 mask: tile row = 128*4B; 128 rows x 32 uint4
#pragma unroll
      for (int i = 0; i < 16; i++) {
        int uidx = i * 256 + threadIdx.x;
        int row = uidx >> 5, col = uidx & 31;
        const uint4* p = (const uint4*)((const char*)mask +
            ((size_t)(qt * 128 + row) * 2048 + ktm * 128) * 4 + col * 16);
        uint4 v = *p;
        nz |= ((v.x | v.y | v.z | v.w) & 0x7fffffffu);
      }
    }
    if (nz) snz = 1;
    __syncthreads();
    if (threadIdx.x == 0) mflags[qt * 16 + ktm] = snz;
  }
}

// ------------------------------------------------------------------ QKV GEMM
// C[4096 x 2304] = A * wqkvT^T, 128x128 tile (m97 pattern), 3 blocks/CU.
// A = x directly when bf16 (device-selected), else the converted xb.
// Epilogue: Q,K -> [b,h,s,d] bf16; V -> V^T [b,h,d,s] f16 via LDS transpose.
__global__ __launch_bounds__(256, 3) void k_gemmQKV(
    const bf16_t* __restrict__ xb, const bf16_t* __restrict__ Bm,
    bf16_t* __restrict__ Qd, bf16_t* __restrict__ Kd, _Float16* __restrict__ Vt,
    const unsigned short* __restrict__ xdet) {
  __shared__ __align__(16) char smem[17408];  // As(8K)+Bs(8K); reused 64x136 f16
  bf16_t* As = (bf16_t*)smem;
  bf16_t* Bs = (bf16_t*)(smem + 8192);
  _Float16* Tb = (_Float16*)smem;

  const int f = detect_bf16_flag(xdet);
  const bf16_t* A = f ? (const bf16_t*)xdet : xb;

  const int tid = threadIdx.x;
  const int n0 = blockIdx.x * 128, m0 = blockIdx.y * 128;
  const int r = tid >> 2, c8 = (tid & 3) << 3;
  const bf16_t* Ag = A + (size_t)(m0 + r) * 768 + c8;
  const bf16_t* Bg = Bm + (size_t)(n0 + r) * 768 + c8;
  const int wid = tid >> 6, lane = tid & 63;
  const int wm = (wid >> 1) << 6, wn = (wid & 1) << 6;
  const int lr = lane & 15, lk = (lane >> 4) << 3, g4 = (lane >> 4) << 2;

  f32x4 acc[4][4];
  const f32x4 z = {0.f, 0.f, 0.f, 0.f};
#pragma unroll
  for (int i = 0; i < 4; i++)
#pragma unroll
    for (int j = 0; j < 4; j++) acc[i][j] = z;

  for (int k0 = 0; k0 < 768; k0 += 32) {
    glds16(Ag + k0, As + wid * 512);
    glds16(Ag + (size_t)64 * 768 + k0, As + 2048 + wid * 512);
    glds16(Bg + k0, Bs + wid * 512);
    glds16(Bg + (size_t)64 * 768 + k0, Bs + 2048 + wid * 512);
    __syncthreads();
    bf16x8 af[4], bf_[4];
#pragma unroll
    for (int t = 0; t < 4; t++) af[t]  = *(const bf16x8*)&As[(wm + t * 16 + lr) * 32 + lk];
#pragma unroll
    for (int t = 0; t < 4; t++) bf_[t] = *(const bf16x8*)&Bs[(wn + t * 16 + lr) * 32 + lk];
#pragma unroll
    for (int i = 0; i < 4; i++)
#pragma unroll
      for (int j = 0; j < 4; j++)
        acc[i][j] = __builtin_amdgcn_mfma_f32_16x16x32_bf16(af[i], bf_[j], acc[i][j], 0, 0, 0);
    __syncthreads();
  }

  if (n0 < 1536) {  // Q or K: scatter (16-lane runs contiguous over d)
    bf16_t* dst = (n0 < 768) ? Qd : Kd;
    const int nb = (n0 < 768) ? n0 : n0 - 768;
    const int bb = m0 >> 11;
#pragma unroll
    for (int i = 0; i < 4; i++)
#pragma unroll
      for (int j = 0; j < 4; j++) {
        const int rc = nb + wn + j * 16 + lr;
        const int hh = rc >> 6, dd = rc & 63;
        const size_t base = (((size_t)bb * 12 + hh) * 2048) * 64 + dd;
#pragma unroll
        for (int reg = 0; reg < 4; reg++) {
          const int s = (m0 & 2047) + wm + i * 16 + g4 + reg;
          dst[base + (size_t)s * 64] = (bf16_t)acc[i][j][reg];
        }
      }
  } else {  // V: LDS transpose -> coalesced V^T f16 writes
    const int bb = m0 >> 11;
#pragma unroll
    for (int half = 0; half < 2; half++) {
      if ((wid & 1) == half) {
#pragma unroll
        for (int j = 0; j < 4; j++) {
          const int d_l = j * 16 + lr;
#pragma unroll
          for (int i = 0; i < 4; i++)
#pragma unroll
            for (int reg = 0; reg < 4; reg++)
              Tb[d_l * 136 + wm + i * 16 + g4 + reg] = (_Float16)acc[i][j][reg];
        }
      }
      __syncthreads();
      const int row = tid >> 2, cc = (tid & 3) * 32;
      const int vcol = (n0 - 1536) + half * 64 + row;
      const int hh = vcol >> 6;  // d == row
      _Float16* dstv = Vt + (((size_t)bb * 12 + hh) * 64 + row) * 2048 + (m0 & 2047) + cc;
#pragma unroll
      for (int u = 0; u < 4; u++)
        *(uint4*)(dstv + u * 8) = *(const uint4*)&Tb[row * 136 + cc + u * 8];
      __syncthreads();
    }
  }
}

// ----------------------------------------------------------- flash attention
// R6 structure: 768 blocks (XCD-swizzled) x 320 threads = 4 consumer waves
// (16 q-rows each) + 1 producer. Producer streams 64-key K (bf16 8KB) +
// V^T (f16 8KB) double-buffered; consumers: S^T = K*Q^T -> in-lane softmax
// (raw v_exp_f32, ballot-gated rescale, pkrtz packing) -> O^T += V^T*P^T.
__global__ __launch_bounds__(320, 4) void k_flash(
    const bf16_t* __restrict__ Qd, const bf16_t* __restrict__ Kd,
    const _Float16* __restrict__ Vt, const void* __restrict__ mask,
    const int* __restrict__ mflags, const unsigned short* __restrict__ xdet,
    bf16_t* __restrict__ attn) {
  __shared__ __align__(16) char sm[32768];  // buf p at p*16384: K 8KB | V 8KB

  const int tid = threadIdx.x, wid = tid >> 6, lane = tid & 63;
  const int lr = lane & 15, quad = lane >> 4, lk = quad << 3, g4 = quad << 2;

  // XCD swizzle: 96 consecutive slots per XCD = 3 (b,h) pairs x 32 qtiles
  const int lin = blockIdx.x;
  const int gx = lin & 7, ww = lin >> 3;
  const int hb = gx * 3 + (ww >> 5);
  const int h = hb % 12, bb = hb / 12;
  const int qt = ww & 31;

  const size_t bh = (size_t)bb * 12 + h;
  const char* Kh = (const char*)(Kd + bh * 2048 * 64);
  const char* Vh = (const char*)(Vt + bh * 64 * 2048);

  if (wid == 4) {
    // ---------------- producer wave
    const char* kS[8]; const char* vS[8];
#pragma unroll
    for (int u = 0; u < 8; u++) {
      const int R = (u >> 1) * 16 + lr;
      const int c = (u & 1) * 4 + quad;
      kS[u] = Kh + R * 128 + c * 16;
      const int u2 = u * 2 + (lane >> 5);
      const int dtv = u2 & 3, ctv = u2 >> 2, j2 = lane & 31;
      vS[u] = Vh + (size_t)(dtv * 16 + (j2 & 15)) * 4096 + ctv * 32 + (j2 >> 4) * 16;
    }
    uint4 kv[8], vv[8];
#pragma unroll
    for (int u = 0; u < 8; u++) kv[u] = *(const uint4*)(kS[u]);
#pragma unroll
    for (int u = 0; u < 8; u++) vv[u] = *(const uint4*)(vS[u]);
#pragma unroll
    for (int u = 0; u < 8; u++) *(uint4*)(sm + u * 1024 + lane * 16) = kv[u];
#pragma unroll
    for (int u = 0; u < 8; u++) *(uint4*)(sm + 8192 + u * 1024 + lane * 16) = vv[u];
    __syncthreads();  // buf0 ready
    for (int s = 0; s < 32; s++) {
      if (s < 31) {
        const int t = s + 1;
        char* buf = sm + (t & 1) * 16384;
#pragma unroll
        for (int u = 0; u < 8; u++) kv[u] = *(const uint4*)(kS[u] + (size_t)t * 8192);
#pragma unroll
        for (int u = 0; u < 8; u++) vv[u] = *(const uint4*)(vS[u] + (size_t)t * 128);
#pragma unroll
        for (int u = 0; u < 8; u++) *(uint4*)(buf + u * 1024 + lane * 16) = kv[u];
#pragma unroll
        for (int u = 0; u < 8; u++) *(uint4*)(buf + 8192 + u * 1024 + lane * 16) = vv[u];
      }
      __syncthreads();
    }
    return;
  }

  // ---------------- consumer waves (wid 0..3), 16 q-rows each
  const bf16_t* Qh = Qd + bh * 2048 * 64;
  const int q0 = qt * 64 + wid * 16;
  const int mbf = detect_bf16_flag(xdet);
  const int* mfrow = mflags + (qt >> 1) * 16;
  int mbits = 0;
#pragma unroll
  for (int t = 0; t < 16; t++) mbits |= (mfrow[t] != 0) << t;  // preload flags

  const bf16x8 qf0 = *(const bf16x8*)&Qh[(size_t)(q0 + lr) * 64 + lk];
  const bf16x8 qf1 = *(const bf16x8*)&Qh[(size_t)(q0 + lr) * 64 + 32 + lk];

  const f32x4 z = {0.f, 0.f, 0.f, 0.f};
  f32x4 ot[4];
#pragma unroll
  for (int dt = 0; dt < 4; dt++) ot[dt] = z;
  float mrow = -1e30f, lrow = 0.f;

  __syncthreads();  // wait buf0

  for (int s = 0; s < 32; s++) {
    const char* Kc = sm + (s & 1) * 16384;
    const char* Vc = Kc + 8192;

    // ---- S^T: sv[ct] C-layout col=q(lr), row=key(ct*16+quad*4+reg)
    f32x4 sv[4];
#pragma unroll
    for (int ct = 0; ct < 4; ct++) sv[ct] = z;
#pragma unroll
    for (int ct = 0; ct < 4; ct++) {
      bf16x8 kf0 = *(const bf16x8*)(Kc + ct * 2048 + lane * 16);
      bf16x8 kf1 = *(const bf16x8*)(Kc + ct * 2048 + 1024 + lane * 16);
      sv[ct] = __builtin_amdgcn_mfma_f32_16x16x32_bf16(kf0, qf0, sv[ct], 0, 0, 0);
      sv[ct] = __builtin_amdgcn_mfma_f32_16x16x32_bf16(kf1, qf1, sv[ct], 0, 0, 0);
    }

    if ((mbits >> (s >> 1)) & 1) {  // generic additive mask (all-zero => skip)
#pragma unroll
      for (int ct = 0; ct < 4; ct++)
#pragma unroll
        for (int reg = 0; reg < 4; reg++) {
          size_t mi = (size_t)(q0 + lr) * 2048 + s * 64 + ct * 16 + g4 + reg;
          float mv = mbf ? bf2f(((const unsigned short*)mask)[mi])
                         : ((const float*)mask)[mi];
          sv[ct][reg] -= 8e9f * mv;
        }
    }

    // ---- row max over 16 in-lane values + xor-16/32
    float t = fmaxf(
        fmaxf(fmaxf(fmaxf(sv[0][0], sv[0][1]), fmaxf(sv[0][2], sv[0][3])),
              fmaxf(fmaxf(sv[1][0], sv[1][1]), fmaxf(sv[1][2], sv[1][3]))),
        fmaxf(fmaxf(fmaxf(sv[2][0], sv[2][1]), fmaxf(sv[2][2], sv[2][3])),
              fmaxf(fmaxf(sv[3][0], sv[3][1]), fmaxf(sv[3][2], sv[3][3]))));
    t = fmaxf(t, __shfl_xor(t, 16));
    t = fmaxf(t, __shfl_xor(t, 32));
    const float mnew = fmaxf(mrow, t);
    // ballot-gated rescale: alpha == 1 exactly when mnew == mrow for all lanes
    if (__ballot(mnew > mrow)) {
      const float alpha = fexp2((mrow - mnew) * SC2);
#pragma unroll
      for (int dt = 0; dt < 4; dt++)
#pragma unroll
        for (int reg = 0; reg < 4; reg++) ot[dt][reg] *= alpha;
      lrow *= alpha;
    }
    mrow = mnew;
    const float mS = mnew * SC2;

    // ---- P^T = exp2(S^T*SC2 - mS), pkrtz-packed f16; row-sum
    float rs = 0.f;
    f16x4 pb[4];
#pragma unroll
    for (int ct = 0; ct < 4; ct++) {
      float p0 = fexp2(fmaf(sv[ct][0], SC2, -mS));
      float p1 = fexp2(fmaf(sv[ct][1], SC2, -mS));
      float p2 = fexp2(fmaf(sv[ct][2], SC2, -mS));
      float p3 = fexp2(fmaf(sv[ct][3], SC2, -mS));
      rs += (p0 + p1) + (p2 + p3);
      union { hf2 h[2]; f16x4 v; } u;
      u.h[0] = __builtin_amdgcn_cvt_pkrtz(p0, p1);
      u.h[1] = __builtin_amdgcn_cvt_pkrtz(p2, p3);
      pb[ct] = u.v;
    }
    rs += __shfl_xor(rs, 16);
    rs += __shfl_xor(rs, 32);
    lrow += rs;

    // ---- PV (contiguous-512B b64 V reads)
#pragma unroll
    for (int ct = 0; ct < 4; ct++) {
#pragma unroll
      for (int dt = 0; dt < 4; dt++) {
        f16x4 va = *(const f16x4*)(Vc + (ct * 4 + dt) * 512 +
                                   (quad >> 1) * 256 + lr * 16 + (quad & 1) * 8);
        ot[dt] = __builtin_amdgcn_mfma_f32_16x16x16f16(va, pb[ct], ot[dt], 0, 0, 0);
      }
    }
    __syncthreads();  // release buf[s&1] to producer
  }

  // ---- normalize + store attn[b*2048+q][h*64+d]
  const float inv = 1.0f / lrow;
  bf16_t* arow = attn + ((size_t)bb * 2048 + q0 + lr) * 768 + h * 64 + g4;
#pragma unroll
  for (int dt = 0; dt < 4; dt++) {
    bf16x4 v;
#pragma unroll
    for (int reg = 0; reg < 4; reg++) v[reg] = (bf16_t)(ot[dt][reg] * inv);
    *(bf16x4*)(arow + dt * 16) = v;
  }
}

// -------------------------------------------------- output GEMM (attn @ Wo^T)
// 64x128 tiles -> 384 blocks; wave tile 32x64 (8 mfma/iter).
__global__ __launch_bounds__(256, 4) void k_gemm2(
    const bf16_t* __restrict__ A, const bf16_t* __restrict__ Bm,
    const void* __restrict__ bo, const unsigned short* __restrict__ xdet,
    float* __restrict__ outF, unsigned short* __restrict__ outH) {
  __shared__ __align__(16) bf16_t As[64 * 32];    // 4KB
  __shared__ __align__(16) bf16_t Bs[128 * 32];   // 8KB
  const int tid = threadIdx.x, wid = tid >> 6, lane = tid & 63;
  const int n0 = blockIdx.x * 128, m0 = blockIdx.y * 64;
  const int wm = (wid >> 1) * 32, wn = (wid & 1) * 64;
  const int lr = lane & 15, lk = (lane >> 4) << 3, g4 = (lane >> 4) << 2;
  const int rr = lane >> 2, c8 = (lane & 3) << 3;
  const bf16_t* Ag  = A + (size_t)(m0 + wid * 16 + rr) * 768 + c8;
  const bf16_t* Bg0 = Bm + (size_t)(n0 + wid * 32 + rr) * 768 + c8;
  const bf16_t* Bg1 = Bm + (size_t)(n0 + wid * 32 + 16 + rr) * 768 + c8;

  f32x4 acc[2][4];
  const f32x4 z = {0.f, 0.f, 0.f, 0.f};
#pragma unroll
  for (int i = 0; i < 2; i++)
#pragma unroll
    for (int j = 0; j < 4; j++) acc[i][j] = z;

  for (int k0 = 0; k0 < 768; k0 += 32) {
    glds16(Ag + k0, As + wid * 512);
    glds16(Bg0 + k0, Bs + wid * 1024);
    glds16(Bg1 + k0, Bs + wid * 1024 + 512);
    __syncthreads();
    bf16x8 af[2], bf_[4];
#pragma unroll
    for (int i = 0; i < 2; i++) af[i]  = *(const bf16x8*)&As[(wm + i * 16 + lr) * 32 + lk];
#pragma unroll
    for (int j = 0; j < 4; j++) bf_[j] = *(const bf16x8*)&Bs[(wn + j * 16 + lr) * 32 + lk];
#pragma unroll
    for (int i = 0; i < 2; i++)
#pragma unroll
      for (int j = 0; j < 4; j++)
        acc[i][j] = __builtin_amdgcn_mfma_f32_16x16x32_bf16(af[i], bf_[j], acc[i][j], 0, 0, 0);
    __syncthreads();
  }

  const int obf = detect_bf16_flag(xdet);
#pragma unroll
  for (int i = 0; i < 2; i++)
#pragma unroll
    for (int j = 0; j < 4; j++) {
      const int nn = n0 + wn + j * 16 + lr;
      const float bv = obf ? bf2f(((const unsigned short*)bo)[nn])
                           : ((const float*)bo)[nn];
#pragma unroll
      for (int reg = 0; reg < 4; reg++) {
        const int m = m0 + wm + i * 16 + g4 + reg;
        const float v = acc[i][j][reg] + bv;
        if (obf) outH[(size_t)m * 768 + nn] = __builtin_bit_cast(unsigned short, (bf16_t)v);
        else     outF[(size_t)m * 768 + nn] = v;
      }
    }
}

// -------------------------------------------------------------------- launch
extern "C" void kernel_launch(void* const* d_in, const int* in_sizes, int n_in,
                              void* d_out, int out_size, void* d_ws, size_t ws_size,
                              hipStream_t stream) {
  (void)in_sizes; (void)n_in; (void)out_size; (void)ws_size;
  const void* x    = d_in[0];
  const void* mask = d_in[1];
  const void* Wq   = d_in[2];
  const void* Wk   = d_in[3];
  const void* Wv   = d_in[4];
  const void* Wo   = d_in[5];
  const void* bo   = d_in[6];

  char* w = (char*)d_ws;
  size_t off = 0;
  auto take = [&](size_t b) -> void* {
    void* p = w + off;
    off = (off + b + 255) & ~(size_t)255;
    return p;
  };
  int*      mflags = (int*)take(256 * 4);
  bf16_t*   wqkvT  = (bf16_t*)take((size_t)2304 * 768 * 2);
  bf16_t*   woT    = (bf16_t*)take((size_t)768 * 768 * 2);
  bf16_t*   xb     = (bf16_t*)take((size_t)4096 * 768 * 2);
  bf16_t*   Qd     = (bf16_t*)take((size_t)3145728 * 2);
  bf16_t*   Kd     = (bf16_t*)take((size_t)3145728 * 2);
  _Float16* Vt     = (_Float16*)take((size_t)3145728 * 2);
  bf16_t*   attn   = xb;  // xb dead after QKV GEMM (flash output reuses it)

  k_prep<<<4096, 256, 0, stream>>>(x, mask, Wq, Wk, Wv, Wo, xb, wqkvT, woT, mflags);
  k_gemmQKV<<<dim3(18, 32), 256, 0, stream>>>(xb, wqkvT, Qd, Kd, Vt,
                                              (const unsigned short*)x);
  k_flash<<<768, 320, 0, stream>>>(Qd, Kd, Vt, mask, mflags,
                                   (const unsigned short*)x, attn);
  k_gemm2<<<dim3(6, 64), 256, 0, stream>>>(attn, woT, bo, (const unsigned short*)x,
                                           (float*)d_out, (unsigned short*)d_out);
}

// Round 10
// 181.951 us; speedup vs baseline: 1.4035x; 1.0248x over previous
//
#include <hip/hip_runtime.h>

// MultiHeadSelfAttention: B=2, S=2048, E=768, H=12, D=64
// R10: (1) gemm2 64x64 tiles, 768 blocks (3/CU) + BK=64; (2) gemmQKV BK=64
//      dual 32-wide LDS sub-buffers (half the barriers, same conflict-free
//      reads); (3) flash row-sum via ones-MFMA (kills 15 adds + 2 shfls per
//      step). Flash otherwise = R9 (59us, verified).

typedef __bf16 bf16_t;
typedef bf16_t bf16x8 __attribute__((ext_vector_type(8)));
typedef bf16_t bf16x4 __attribute__((ext_vector_type(4)));
typedef float f32x4 __attribute__((ext_vector_type(4)));
typedef _Float16 f16x4 __attribute__((ext_vector_type(4)));
typedef __fp16 hf2 __attribute__((ext_vector_type(2)));

#define SC2 0.1803368801111137f  // 0.125 * log2(e): qk-scale folded into exp2

__device__ __forceinline__ float bf2f(unsigned short u) {
  union { unsigned int i; float f; } x;
  x.i = ((unsigned int)u) << 16;
  return x.f;
}

__device__ __forceinline__ float fexp2(float x) {
  return __builtin_amdgcn_exp2f(x);  // raw v_exp_f32; args <= 0 here, FTZ exact
}

__device__ __forceinline__ void glds16(const bf16_t* g, bf16_t* l) {
  __builtin_amdgcn_global_load_lds(
      (const __attribute__((address_space(1))) void*)g,
      (__attribute__((address_space(3))) void*)l, 16, 0, 0);
}

// dtype probe: wave examines first 1024 u16 words of x. fp32 data => low
// halves carry random mantissa bits => wild bf16 exponents.
__device__ __forceinline__ int detect_bf16_flag(const unsigned short* x) {
  const int lane = threadIdx.x & 63;
  const uint4* p = (const uint4*)x;
  uint4 a = p[lane * 2];
  uint4 b = p[lane * 2 + 1];
  unsigned int w[8] = {a.x, a.y, a.z, a.w, b.x, b.y, b.z, b.w};
  unsigned int big = 0;
#pragma unroll
  for (int i = 0; i < 8; i++) {
    unsigned int e0 = (w[i] >> 7) & 0xFF, e1 = (w[i] >> 23) & 0xFF;
    big |= (e0 > 0x88u) | (e1 > 0x88u);
  }
  unsigned long long bal = __ballot(big != 0u);
  return bal == 0ULL ? 1 : 0;  // 1 => bf16 inputs
}

// ---------------------------------------------------------------- fused prep
// blocks [0,1536): x -> xb bf16 (skipped when bf16) | [1536,3840): W transposes
// | [3840,4096): maskflags (vectorized uint4 scan)
__global__ void k_prep(const void* __restrict__ x, const void* __restrict__ mask,
                       const void* __restrict__ Wq, const void* __restrict__ Wk,
                       const void* __restrict__ Wv, const void* __restrict__ Wo,
                       bf16_t* __restrict__ xb, bf16_t* __restrict__ wqkvT,
                       bf16_t* __restrict__ woT, int* __restrict__ mflags) {
  __shared__ float ts[32][33];
  __shared__ int snz;
  const int blk = blockIdx.x;
  const int f = detect_bf16_flag((const unsigned short*)x);

  if (blk < 1536) {  // ---- ingest x (fp32 only; bf16 path reads x directly)
    if (f) return;
    int i = blk * 256 + threadIdx.x;
    const float* xf = (const float*)x + (size_t)i * 8;
    bf16x8 v;
#pragma unroll
    for (int j = 0; j < 8; j++) v[j] = (bf16_t)xf[j];
    *(bf16x8*)(xb + (size_t)i * 8) = v;
  } else if (blk < 3840) {  // ---- W transpose (4 matrices x 24x24 tiles)
    const int t = blk - 1536;
    const int z = t / 576, r = t % 576, kt = r / 24, nt = r % 24;
    const void* wsrc = (z == 0) ? Wq : (z == 1) ? Wk : (z == 2) ? Wv : Wo;
    bf16_t* dst = (z < 3) ? (wqkvT + (size_t)z * 768 * 768) : woT;
    const int c = threadIdx.x & 31, r0 = threadIdx.x >> 5;
#pragma unroll
    for (int i = 0; i < 4; i++) {
      int kr = kt * 32 + r0 + i * 8;
      float v;
      if (f) v = bf2f(((const unsigned short*)wsrc)[(size_t)kr * 768 + nt * 32 + c]);
      else   v = ((const float*)wsrc)[(size_t)kr * 768 + nt * 32 + c];
      ts[r0 + i * 8][c] = v;
    }
    __syncthreads();
#pragma unroll
    for (int i = 0; i < 4; i++) {
      int nr = nt * 32 + r0 + i * 8;
      dst[(size_t)nr * 768 + kt * 32 + c] = (bf16_t)ts[c][r0 + i * 8];
    }
  } else {  // ---- mask nonzero flag per 128x128 tile, uint4 loads
    const int t = blk - 3840;
    const int qt = t >> 4, ktm = t & 15;
    if (threadIdx.x == 0) snz = 0;
    __syncthreads();
    unsigned int nz = 0;
    if (f) {
#pragma unroll
      for (int i = 0; i < 8; i++) {
        int uidx = i * 256 + threadIdx.x;
        int row = uidx >> 4, col = uidx & 15;
        const uint4* p = (const uint4*)((const char*)mask +
            ((size_t)(qt * 128 + row) * 2048 + ktm * 128) * 2 + col * 16);
        uint4 v = *p;
        nz |= ((v.x | v.y | v.z | v.w) & 0x7fff7fffu);
      }
    } else {
#pragma unroll
      for (int i = 0; i < 16; i++) {
        int uidx = i * 256 + threadIdx.x;
        int row = uidx >> 5, col = uidx & 31;
        const uint4* p = (const uint4*)((const char*)mask +
            ((size_t)(qt * 128 + row) * 2048 + ktm * 128) * 4 + col * 16);
        uint4 v = *p;
        nz |= ((v.x | v.y | v.z | v.w) & 0x7fffffffu);
      }
    }
    if (nz) snz = 1;
    __syncthreads();
    if (threadIdx.x == 0) mflags[qt * 16 + ktm] = snz;
  }
}

// ------------------------------------------------------------------ QKV GEMM
// C[4096 x 2304] = A * wqkvT^T, 128x128 tile, BK=64 via two 32-wide LDS
// sub-buffers (identical conflict-free ds_read_b128 pattern, half barriers).
// A = x directly when bf16 (device-selected), else converted xb.
__global__ __launch_bounds__(256, 3) void k_gemmQKV(
    const bf16_t* __restrict__ xb, const bf16_t* __restrict__ Bm,
    bf16_t* __restrict__ Qd, bf16_t* __restrict__ Kd, _Float16* __restrict__ Vt,
    const unsigned short* __restrict__ xdet) {
  __shared__ __align__(16) char smem[32768];  // As0|As1|Bs0|Bs1 8KB each
  bf16_t* As0 = (bf16_t*)smem;
  bf16_t* As1 = (bf16_t*)(smem + 8192);
  bf16_t* Bs0 = (bf16_t*)(smem + 16384);
  bf16_t* Bs1 = (bf16_t*)(smem + 24576);
  _Float16* Tb = (_Float16*)smem;

  const int f = detect_bf16_flag(xdet);
  const bf16_t* A = f ? (const bf16_t*)xdet : xb;

  const int tid = threadIdx.x;
  const int n0 = blockIdx.x * 128, m0 = blockIdx.y * 128;
  const int r = tid >> 2, c8 = (tid & 3) << 3;
  const bf16_t* Ag = A + (size_t)(m0 + r) * 768 + c8;
  const bf16_t* Bg = Bm + (size_t)(n0 + r) * 768 + c8;
  const int wid = tid >> 6, lane = tid & 63;
  const int wm = (wid >> 1) << 6, wn = (wid & 1) << 6;
  const int lr = lane & 15, lk = (lane >> 4) << 3, g4 = (lane >> 4) << 2;

  f32x4 acc[4][4];
  const f32x4 z = {0.f, 0.f, 0.f, 0.f};
#pragma unroll
  for (int i = 0; i < 4; i++)
#pragma unroll
    for (int j = 0; j < 4; j++) acc[i][j] = z;

  for (int k0 = 0; k0 < 768; k0 += 64) {
    glds16(Ag + k0, As0 + wid * 512);
    glds16(Ag + (size_t)64 * 768 + k0, As0 + 2048 + wid * 512);
    glds16(Ag + k0 + 32, As1 + wid * 512);
    glds16(Ag + (size_t)64 * 768 + k0 + 32, As1 + 2048 + wid * 512);
    glds16(Bg + k0, Bs0 + wid * 512);
    glds16(Bg + (size_t)64 * 768 + k0, Bs0 + 2048 + wid * 512);
    glds16(Bg + k0 + 32, Bs1 + wid * 512);
    glds16(Bg + (size_t)64 * 768 + k0 + 32, Bs1 + 2048 + wid * 512);
    __syncthreads();
#pragma unroll
    for (int kc = 0; kc < 2; kc++) {
      const bf16_t* Asb = kc ? As1 : As0;
      const bf16_t* Bsb = kc ? Bs1 : Bs0;
      bf16x8 af[4], bf_[4];
#pragma unroll
      for (int t = 0; t < 4; t++) af[t]  = *(const bf16x8*)&Asb[(wm + t * 16 + lr) * 32 + lk];
#pragma unroll
      for (int t = 0; t < 4; t++) bf_[t] = *(const bf16x8*)&Bsb[(wn + t * 16 + lr) * 32 + lk];
#pragma unroll
      for (int i = 0; i < 4; i++)
#pragma unroll
        for (int j = 0; j < 4; j++)
          acc[i][j] = __builtin_amdgcn_mfma_f32_16x16x32_bf16(af[i], bf_[j], acc[i][j], 0, 0, 0);
    }
    __syncthreads();
  }

  if (n0 < 1536) {  // Q or K: scatter (16-lane runs contiguous over d)
    bf16_t* dst = (n0 < 768) ? Qd : Kd;
    const int nb = (n0 < 768) ? n0 : n0 - 768;
    const int bb = m0 >> 11;
#pragma unroll
    for (int i = 0; i < 4; i++)
#pragma unroll
      for (int j = 0; j < 4; j++) {
        const int rc = nb + wn + j * 16 + lr;
        const int hh = rc >> 6, dd = rc & 63;
        const size_t base = (((size_t)bb * 12 + hh) * 2048) * 64 + dd;
#pragma unroll
        for (int reg = 0; reg < 4; reg++) {
          const int s = (m0 & 2047) + wm + i * 16 + g4 + reg;
          dst[base + (size_t)s * 64] = (bf16_t)acc[i][j][reg];
        }
      }
  } else {  // V: LDS transpose -> coalesced V^T f16 writes
    const int bb = m0 >> 11;
#pragma unroll
    for (int half = 0; half < 2; half++) {
      if ((wid & 1) == half) {
#pragma unroll
        for (int j = 0; j < 4; j++) {
          const int d_l = j * 16 + lr;
#pragma unroll
          for (int i = 0; i < 4; i++)
#pragma unroll
            for (int reg = 0; reg < 4; reg++)
              Tb[d_l * 136 + wm + i * 16 + g4 + reg] = (_Float16)acc[i][j][reg];
        }
      }
      __syncthreads();
      const int row = tid >> 2, cc = (tid & 3) * 32;
      const int vcol = (n0 - 1536) + half * 64 + row;
      const int hh = vcol >> 6;  // d == row
      _Float16* dstv = Vt + (((size_t)bb * 12 + hh) * 64 + row) * 2048 + (m0 & 2047) + cc;
#pragma unroll
      for (int u = 0; u < 4; u++)
        *(uint4*)(dstv + u * 8) = *(const uint4*)&Tb[row * 136 + cc + u * 8];
      __syncthreads();
    }
  }
}

// ----------------------------------------------------------- flash attention
// R9 structure (768 blocks x 320 thr, 4 consumers + producer, double-buffer)
// with row-sum computed by a ones-MFMA instead of 15 adds + 2 shfls.
__global__ __launch_bounds__(320, 4) void k_flash(
    const bf16_t* __restrict__ Qd, const bf16_t* __restrict__ Kd,
    const _Float16* __restrict__ Vt, const void* __restrict__ mask,
    const int* __restrict__ mflags, const unsigned short* __restrict__ xdet,
    bf16_t* __restrict__ attn) {
  __shared__ __align__(16) char sm[32768];  // buf p at p*16384: K 8KB | V 8KB

  const int tid = threadIdx.x, wid = tid >> 6, lane = tid & 63;
  const int lr = lane & 15, quad = lane >> 4, lk = quad << 3, g4 = quad << 2;

  // XCD swizzle: 96 consecutive slots per XCD = 3 (b,h) pairs x 32 qtiles
  const int lin = blockIdx.x;
  const int gx = lin & 7, ww = lin >> 3;
  const int hb = gx * 3 + (ww >> 5);
  const int h = hb % 12, bb = hb / 12;
  const int qt = ww & 31;

  const size_t bh = (size_t)bb * 12 + h;
  const char* Kh = (const char*)(Kd + bh * 2048 * 64);
  const char* Vh = (const char*)(Vt + bh * 64 * 2048);

  if (wid == 4) {
    // ---------------- producer wave
    const char* kS[8]; const char* vS[8];
#pragma unroll
    for (int u = 0; u < 8; u++) {
      const int R = (u >> 1) * 16 + lr;
      const int c = (u & 1) * 4 + quad;
      kS[u] = Kh + R * 128 + c * 16;
      const int u2 = u * 2 + (lane >> 5);
      const int dtv = u2 & 3, ctv = u2 >> 2, j2 = lane & 31;
      vS[u] = Vh + (size_t)(dtv * 16 + (j2 & 15)) * 4096 + ctv * 32 + (j2 >> 4) * 16;
    }
    uint4 kv[8], vv[8];
#pragma unroll
    for (int u = 0; u < 8; u++) kv[u] = *(const uint4*)(kS[u]);
#pragma unroll
    for (int u = 0; u < 8; u++) vv[u] = *(const uint4*)(vS[u]);
#pragma unroll
    for (int u = 0; u < 8; u++) *(uint4*)(sm + u * 1024 + lane * 16) = kv[u];
#pragma unroll
    for (int u = 0; u < 8; u++) *(uint4*)(sm + 8192 + u * 1024 + lane * 16) = vv[u];
    __syncthreads();  // buf0 ready
    for (int s = 0; s < 32; s++) {
      if (s < 31) {
        const int t = s + 1;
        char* buf = sm + (t & 1) * 16384;
#pragma unroll
        for (int u = 0; u < 8; u++) kv[u] = *(const uint4*)(kS[u] + (size_t)t * 8192);
#pragma unroll
        for (int u = 0; u < 8; u++) vv[u] = *(const uint4*)(vS[u] + (size_t)t * 128);
#pragma unroll
        for (int u = 0; u < 8; u++) *(uint4*)(buf + u * 1024 + lane * 16) = kv[u];
#pragma unroll
        for (int u = 0; u < 8; u++) *(uint4*)(buf + 8192 + u * 1024 + lane * 16) = vv[u];
      }
      __syncthreads();
    }
    return;
  }

  // ---------------- consumer waves (wid 0..3), 16 q-rows each
  const bf16_t* Qh = Qd + bh * 2048 * 64;
  const int q0 = qt * 64 + wid * 16;
  const int mbf = detect_bf16_flag(xdet);
  const int* mfrow = mflags + (qt >> 1) * 16;
  int mbits = 0;
#pragma unroll
  for (int t = 0; t < 16; t++) mbits |= (mfrow[t] != 0) << t;  // preload flags

  const bf16x8 qf0 = *(const bf16x8*)&Qh[(size_t)(q0 + lr) * 64 + lk];
  const bf16x8 qf1 = *(const bf16x8*)&Qh[(size_t)(q0 + lr) * 64 + 32 + lk];

  f16x4 ones;
  ones[0] = (_Float16)1.f; ones[1] = (_Float16)1.f;
  ones[2] = (_Float16)1.f; ones[3] = (_Float16)1.f;

  const f32x4 z = {0.f, 0.f, 0.f, 0.f};
  f32x4 ot[4];
#pragma unroll
  for (int dt = 0; dt < 4; dt++) ot[dt] = z;
  float mrow = -1e30f, lrow = 0.f;

  __syncthreads();  // wait buf0

  for (int s = 0; s < 32; s++) {
    const char* Kc = sm + (s & 1) * 16384;
    const char* Vc = Kc + 8192;

    // ---- S^T: sv[ct] C-layout col=q(lr), row=key(ct*16+quad*4+reg)
    f32x4 sv[4];
#pragma unroll
    for (int ct = 0; ct < 4; ct++) sv[ct] = z;
#pragma unroll
    for (int ct = 0; ct < 4; ct++) {
      bf16x8 kf0 = *(const bf16x8*)(Kc + ct * 2048 + lane * 16);
      bf16x8 kf1 = *(const bf16x8*)(Kc + ct * 2048 + 1024 + lane * 16);
      sv[ct] = __builtin_amdgcn_mfma_f32_16x16x32_bf16(kf0, qf0, sv[ct], 0, 0, 0);
      sv[ct] = __builtin_amdgcn_mfma_f32_16x16x32_bf16(kf1, qf1, sv[ct], 0, 0, 0);
    }

    if ((mbits >> (s >> 1)) & 1) {  // generic additive mask (all-zero => skip)
#pragma unroll
      for (int ct = 0; ct < 4; ct++)
#pragma unroll
        for (int reg = 0; reg < 4; reg++) {
          size_t mi = (size_t)(q0 + lr) * 2048 + s * 64 + ct * 16 + g4 + reg;
          float mv = mbf ? bf2f(((const unsigned short*)mask)[mi])
                         : ((const float*)mask)[mi];
          sv[ct][reg] -= 8e9f * mv;
        }
    }

    // ---- row max over 16 in-lane values + xor-16/32
    float t = fmaxf(
        fmaxf(fmaxf(fmaxf(sv[0][0], sv[0][1]), fmaxf(sv[0][2], sv[0][3])),
              fmaxf(fmaxf(sv[1][0], sv[1][1]), fmaxf(sv[1][2], sv[1][3]))),
        fmaxf(fmaxf(fmaxf(sv[2][0], sv[2][1]), fmaxf(sv[2][2], sv[2][3])),
              fmaxf(fmaxf(sv[3][0], sv[3][1]), fmaxf(sv[3][2], sv[3][3]))));
    t = fmaxf(t, __shfl_xor(t, 16));
    t = fmaxf(t, __shfl_xor(t, 32));
    const float mnew = fmaxf(mrow, t);
    if (__ballot(mnew > mrow)) {
      const float alpha = fexp2((mrow - mnew) * SC2);
#pragma unroll
      for (int dt = 0; dt < 4; dt++)
#pragma unroll
        for (int reg = 0; reg < 4; reg++) ot[dt][reg] *= alpha;
      lrow *= alpha;
    }
    mrow = mnew;
    const float mS = mnew * SC2;

    // ---- P^T = exp2(S^T*SC2 - mS), pkrtz-packed f16 (row-sum via MFMA below)
    f16x4 pb[4];
#pragma unroll
    for (int ct = 0; ct < 4; ct++) {
      float p0 = fexp2(fmaf(sv[ct][0], SC2, -mS));
      float p1 = fexp2(fmaf(sv[ct][1], SC2, -mS));
      float p2 = fexp2(fmaf(sv[ct][2], SC2, -mS));
      float p3 = fexp2(fmaf(sv[ct][3], SC2, -mS));
      union { hf2 h[2]; f16x4 v; } u;
      u.h[0] = __builtin_amdgcn_cvt_pkrtz(p0, p1);
      u.h[1] = __builtin_amdgcn_cvt_pkrtz(p2, p3);
      pb[ct] = u.v;
    }

    // ---- PV + ones-MFMA row-sum (acc_sum rows all equal rowsum(q=lr))
    f32x4 asum = z;
#pragma unroll
    for (int ct = 0; ct < 4; ct++) {
      asum = __builtin_amdgcn_mfma_f32_16x16x16f16(ones, pb[ct], asum, 0, 0, 0);
#pragma unroll
      for (int dt = 0; dt < 4; dt++) {
        f16x4 va = *(const f16x4*)(Vc + (ct * 4 + dt) * 512 +
                                   (quad >> 1) * 256 + lr * 16 + (quad & 1) * 8);
        ot[dt] = __builtin_amdgcn_mfma_f32_16x16x16f16(va, pb[ct], ot[dt], 0, 0, 0);
      }
    }
    lrow += asum[0];
    __syncthreads();  // release buf[s&1] to producer
  }

  // ---- normalize + store attn[b*2048+q][h*64+d]
  const float inv = 1.0f / lrow;
  bf16_t* arow = attn + ((size_t)bb * 2048 + q0 + lr) * 768 + h * 64 + g4;
#pragma unroll
  for (int dt = 0; dt < 4; dt++) {
    bf16x4 v;
#pragma unroll
    for (int reg = 0; reg < 4; reg++) v[reg] = (bf16_t)(ot[dt][reg] * inv);
    *(bf16x4*)(arow + dt * 16) = v;
  }
}

// -------------------------------------------------- output GEMM (attn @ Wo^T)
// 64x64 tiles -> grid (12,64) = 768 blocks (3/CU, 12 waves/CU), BK=64.
__global__ __launch_bounds__(256, 3) void k_gemm2(
    const bf16_t* __restrict__ A, const bf16_t* __restrict__ Bm,
    const void* __restrict__ bo, const unsigned short* __restrict__ xdet,
    float* __restrict__ outF, unsigned short* __restrict__ outH) {
  __shared__ __align__(16) char smem[16384];  // As0|As1|Bs0|Bs1 4KB each
  bf16_t* As0 = (bf16_t*)smem;
  bf16_t* As1 = (bf16_t*)(smem + 4096);
  bf16_t* Bs0 = (bf16_t*)(smem + 8192);
  bf16_t* Bs1 = (bf16_t*)(smem + 12288);

  const int tid = threadIdx.x, wid = tid >> 6, lane = tid & 63;
  const int n0 = blockIdx.x * 64, m0 = blockIdx.y * 64;
  const int wm = (wid >> 1) << 5, wn = (wid & 1) << 5;
  const int lr = lane & 15, lk = (lane >> 4) << 3, g4 = (lane >> 4) << 2;
  const int rr = lane >> 2, c8 = (lane & 3) << 3;
  const bf16_t* Ag = A + (size_t)(m0 + wid * 16 + rr) * 768 + c8;
  const bf16_t* Bg = Bm + (size_t)(n0 + wid * 16 + rr) * 768 + c8;

  f32x4 acc[2][2];
  const f32x4 z = {0.f, 0.f, 0.f, 0.f};
#pragma unroll
  for (int i = 0; i < 2; i++)
#pragma unroll
    for (int j = 0; j < 2; j++) acc[i][j] = z;

  for (int k0 = 0; k0 < 768; k0 += 64) {
    glds16(Ag + k0, As0 + wid * 512);
    glds16(Ag + k0 + 32, As1 + wid * 512);
    glds16(Bg + k0, Bs0 + wid * 512);
    glds16(Bg + k0 + 32, Bs1 + wid * 512);
    __syncthreads();
#pragma unroll
    for (int kc = 0; kc < 2; kc++) {
      const bf16_t* Asb = kc ? As1 : As0;
      const bf16_t* Bsb = kc ? Bs1 : Bs0;
      bf16x8 af[2], bf_[2];
#pragma unroll
      for (int i = 0; i < 2; i++) af[i]  = *(const bf16x8*)&Asb[(wm + i * 16 + lr) * 32 + lk];
#pragma unroll
      for (int j = 0; j < 2; j++) bf_[j] = *(const bf16x8*)&Bsb[(wn + j * 16 + lr) * 32 + lk];
#pragma unroll
      for (int i = 0; i < 2; i++)
#pragma unroll
        for (int j = 0; j < 2; j++)
          acc[i][j] = __builtin_amdgcn_mfma_f32_16x16x32_bf16(af[i], bf_[j], acc[i][j], 0, 0, 0);
    }
    __syncthreads();
  }

  const int obf = detect_bf16_flag(xdet);
#pragma unroll
  for (int i = 0; i < 2; i++)
#pragma unroll
    for (int j = 0; j < 2; j++) {
      const int nn = n0 + wn + j * 16 + lr;
      const float bv = obf ? bf2f(((const unsigned short*)bo)[nn])
                           : ((const float*)bo)[nn];
#pragma unroll
      for (int reg = 0; reg < 4; reg++) {
        const int m = m0 + wm + i * 16 + g4 + reg;
        const float v = acc[i][j][reg] + bv;
        if (obf) outH[(size_t)m * 768 + nn] = __builtin_bit_cast(unsigned short, (bf16_t)v);
        else     outF[(size_t)m * 768 + nn] = v;
      }
    }
}

// -------------------------------------------------------------------- launch
extern "C" void kernel_launch(void* const* d_in, const int* in_sizes, int n_in,
                              void* d_out, int out_size, void* d_ws, size_t ws_size,
                              hipStream_t stream) {
  (void)in_sizes; (void)n_in; (void)out_size; (void)ws_size;
  const void* x    = d_in[0];
  const void* mask = d_in[1];
  const void* Wq   = d_in[2];
  const void* Wk   = d_in[3];
  const void* Wv   = d_in[4];
  const void* Wo   = d_in[5];
  const void* bo   = d_in[6];

  char* w = (char*)d_ws;
  size_t off = 0;
  auto take = [&](size_t b) -> void* {
    void* p = w + off;
    off = (off + b + 255) & ~(size_t)255;
    return p;
  };
  int*      mflags = (int*)take(256 * 4);
  bf16_t*   wqkvT  = (bf16_t*)take((size_t)2304 * 768 * 2);
  bf16_t*   woT    = (bf16_t*)take((size_t)768 * 768 * 2);
  bf16_t*   xb     = (bf16_t*)take((size_t)4096 * 768 * 2);
  bf16_t*   Qd     = (bf16_t*)take((size_t)3145728 * 2);
  bf16_t*   Kd     = (bf16_t*)take((size_t)3145728 * 2);
  _Float16* Vt     = (_Float16*)take((size_t)3145728 * 2);
  bf16_t*   attn   = xb;  // xb dead after QKV GEMM (flash output reuses it)

  k_prep<<<4096, 256, 0, stream>>>(x, mask, Wq, Wk, Wv, Wo, xb, wqkvT, woT, mflags);
  k_gemmQKV<<<dim3(18, 32), 256, 0, stream>>>(xb, wqkvT, Qd, Kd, Vt,
                                              (const unsigned short*)x);
  k_flash<<<768, 320, 0, stream>>>(Qd, Kd, Vt, mask, mflags,
                                   (const unsigned short*)x, attn);
  k_gemm2<<<dim3(12, 64), 256, 0, stream>>>(attn, woT, bo, (const unsigned short*)x,
                                            (float*)d_out, (unsigned short*)d_out);
}